// Round 5
// baseline (634.314 us; speedup 1.0000x reference)
//
#include <hip/hip_runtime.h>
#include <hip/hip_bf16.h>

#define DEVI __device__ __forceinline__

typedef __attribute__((ext_vector_type(8))) short  short8;
typedef __attribute__((ext_vector_type(4))) float  floatx4;
typedef __attribute__((ext_vector_type(8))) __bf16 bf16x8;

DEVI float b2f(unsigned short u){ union{unsigned int i; float f;} x; x.i=((unsigned int)u)<<16; return x.f; }
DEVI unsigned short f2b(float f){
  union{float ff; unsigned int i;} x; x.ff=f;
  unsigned int r = x.i + 0x7fffu + ((x.i>>16)&1u);
  return (unsigned short)(r>>16);
}

DEVI void lds_dma16(const void* g, void* l){
  __builtin_amdgcn_global_load_lds((const __attribute__((address_space(1))) void*)g,
                                   (__attribute__((address_space(3))) void*)l, 16, 0, 0);
}

DEVI floatx4 mfma_bf16(short8 a, short8 b, floatx4 c){
  return __builtin_amdgcn_mfma_f32_16x16x32_bf16(
      __builtin_bit_cast(bf16x8, a), __builtin_bit_cast(bf16x8, b), c, 0, 0, 0);
}

// XCD-chunked tile remap (T1). Verified round 4: FETCH 266MB -> 65.6MB.
DEVI void tile_remap(long& bmi, long& bni){
  const int bx = blockIdx.x, by = blockIdx.y;
  if (gridDim.y == 128){
    bni = (long)(by & 7);
    bmi = (long)((bx << 4) + (by >> 3));
  } else {
    bni = bx; bmi = by;
  }
}

// Double-buffered BK=32 K-loop (T3 minimum-2-phase): stage tile t+1 into
// buf[o^1] BEFORE computing buf[o]; ONE barrier per iteration. The barrier's
// vmcnt(0)/lgkmcnt(0) drains stage traffic that had the whole MFMA phase to
// complete. LDS swizzle for [128][32] tiles: slot(row,cr) holds global chunk
// cr ^ ((row>>1)&3); DMA dest linear (base + lane*16), SOURCE column
// inverse-permuted; read offset (kg*8) ^ (((l15>>1)&3)*8).

// ---------------------------------------------------------------------------
// f32 -> bf16 (single) elementwise
// ---------------------------------------------------------------------------
__global__ void cvt_kernel(const float* __restrict__ src, unsigned short* __restrict__ dst, int n8)
{
  const int i = blockIdx.x * 256 + threadIdx.x;
  if (i >= n8) return;
  floatx4 a = ((const floatx4*)src)[2*(size_t)i];
  floatx4 b = ((const floatx4*)src)[2*(size_t)i + 1];
  short8 o;
  o[0]=(short)f2b(a[0]); o[1]=(short)f2b(a[1]); o[2]=(short)f2b(a[2]); o[3]=(short)f2b(a[3]);
  o[4]=(short)f2b(b[0]); o[5]=(short)f2b(b[1]); o[6]=(short)f2b(b[2]); o[7]=(short)f2b(b[3]);
  *(short8*)&dst[(size_t)i*8] = o;
}

// ---------------------------------------------------------------------------
// f32 -> (hi, lo) bf16 split: hi = rne(x), lo = rne(x - hi).
// ---------------------------------------------------------------------------
__global__ void cvt_split(const float* __restrict__ src, unsigned short* __restrict__ dh,
                          unsigned short* __restrict__ dl, int n8)
{
  const int i = blockIdx.x * 256 + threadIdx.x;
  if (i >= n8) return;
  floatx4 a = ((const floatx4*)src)[2*(size_t)i];
  floatx4 b = ((const floatx4*)src)[2*(size_t)i + 1];
  short8 h, l;
  #pragma unroll
  for (int j = 0; j < 8; j++){
    float x = (j < 4) ? a[j] : b[j-4];
    unsigned short hb = f2b(x);
    h[j] = (short)hb;
    l[j] = (short)f2b(x - b2f(hb));
  }
  *(short8*)&dh[(size_t)i*8] = h;
  *(short8*)&dl[(size_t)i*8] = l;
}

// ---------------------------------------------------------------------------
// C(bf16) = A(f32) @ Bw(bf16)^T.  Dbuf BK=32, swizzled LDS, XCD remap,
// 3 blocks/CU. GATE=1: fused z*silu epilogue.
// ---------------------------------------------------------------------------
template<int GATE>
__global__ __launch_bounds__(256, 3)
void gemm_af32(const float* __restrict__ A, const unsigned short* __restrict__ Bw,
               unsigned short* __restrict__ C, int M, int N, int K,
               const float* __restrict__ zs, const float* __restrict__ zc)
{
  __shared__ __align__(16) short As[2][128*32];
  __shared__ __align__(16) short Bs[2][128*32];
  const int t    = threadIdx.x;
  const int lane = t & 63;
  const int w    = t >> 6, wm = w >> 1, wn = w & 1;
  const int l15  = lane & 15, kg = lane >> 4;
  const int sxr  = ((l15 >> 1) & 3) * 8;            // read-side swizzle
  long bmi, bni; tile_remap(bmi, bni);
  const long bm = bmi * 128, bn = bni * 128;

  // B staging: 2 DMA calls; linear dest, inverse-swizzled source column.
  size_t bgo[2]; int bls[2];
  #pragma unroll
  for (int u = 0; u < 2; u++){
    const int cl  = u*256 + t;
    const int row = cl >> 2, cr = cl & 3;
    const int csrc = cr ^ ((row >> 1) & 3);
    bgo[u] = (size_t)(bn + row) * K + csrc*8;
    bls[u] = cl * 8;
  }
  // A staging: thread t -> row t>>1, 16 f32; swizzled ds_write slots.
  const int arow = t >> 1, acolb = (t & 1) * 16;
  const float* pa = A + (bm + arow) * (size_t)K + acolb;
  const int aw0 = arow*32 + ((((t&1)*2    ) ^ ((t>>2)&3)))*8;
  const int aw1 = arow*32 + ((((t&1)*2 + 1) ^ ((t>>2)&3)))*8;

  floatx4 acc[4][4] = {};
  floatx4 sta[4], stb[4];

  // prologue: stage tile 0 into buf 0; prefetch A(1) into regs.
  #pragma unroll
  for (int u = 0; u < 2; u++) lds_dma16(Bw + bgo[u], &Bs[0][bls[u]]);
  #pragma unroll
  for (int u = 0; u < 4; u++) sta[u] = *(const floatx4*)(pa + u*4);
  {
    short8 h0, h1;
    #pragma unroll
    for (int j = 0; j < 8; j++){
      h0[j] = (short)f2b(sta[j>>2][j&3]);
      h1[j] = (short)f2b(sta[2 + (j>>2)][j&3]);
    }
    *(short8*)&As[0][aw0] = h0; *(short8*)&As[0][aw1] = h1;
  }
  #pragma unroll
  for (int u = 0; u < 4; u++) sta[u] = *(const floatx4*)(pa + 32 + u*4);
  __syncthreads();

  const int NT = K >> 5;
  int o = 0;
  for (int kt = 0; kt < NT; ++kt){
    if (kt + 1 < NT){
      // stage tile kt+1 into buf o^1 (overlaps this iter's MFMAs).
      short8 h0, h1;
      #pragma unroll
      for (int j = 0; j < 8; j++){
        h0[j] = (short)f2b(sta[j>>2][j&3]);
        h1[j] = (short)f2b(sta[2 + (j>>2)][j&3]);
      }
      *(short8*)&As[o^1][aw0] = h0; *(short8*)&As[o^1][aw1] = h1;
      const int k1 = (kt + 1) << 5;
      #pragma unroll
      for (int u = 0; u < 2; u++) lds_dma16(Bw + bgo[u] + k1, &Bs[o^1][bls[u]]);
      const int k2 = ((kt + 2 < NT) ? (kt + 2) : kt) << 5;
      #pragma unroll
      for (int u = 0; u < 4; u++) stb[u] = *(const floatx4*)(pa + k2 + u*4);
    }
    short8 af[4], bv[4];
    #pragma unroll
    for (int i = 0; i < 4; i++){
      af[i] = *(const short8*)&As[o][(wm*64 + i*16 + l15)*32 + ((kg*8) ^ sxr)];
      bv[i] = *(const short8*)&Bs[o][(wn*64 + i*16 + l15)*32 + ((kg*8) ^ sxr)];
    }
    #pragma unroll
    for (int i = 0; i < 4; i++)
      #pragma unroll
      for (int j = 0; j < 4; j++)
        acc[i][j] = mfma_bf16(af[i], bv[j], acc[i][j]);
    __syncthreads();
    o ^= 1;
    #pragma unroll
    for (int u = 0; u < 4; u++) sta[u] = stb[u];
  }

  if (GATE){
    #pragma unroll
    for (int i = 0; i < 4; i++){
      const long mb = bm + wm*64 + i*16 + kg*4;
      #pragma unroll
      for (int r = 0; r < 4; r++){
        const long row = mb + r;
        const int  ss  = (int)(row & 4095);
        const long bb  = row >> 12;
        const float* zr = (ss < 64) ? (zs + (((size_t)(bb*64 + ss)) << 10))
                                    : (zc + ((size_t)bb << 10));
        #pragma unroll
        for (int j = 0; j < 4; j++){
          const long n = bn + wn*64 + j*16 + l15;
          float g = acc[i][j][r] * zr[n];
          float sig = 1.0f / (1.0f + __expf(-g));
          C[(size_t)row * N + n] = f2b(g * sig);
        }
      }
    }
  } else {
    #pragma unroll
    for (int i = 0; i < 4; i++){
      const long mb = bm + wm*64 + i*16 + kg*4;
      #pragma unroll
      for (int j = 0; j < 4; j++){
        const long n = bn + wn*64 + j*16 + l15;
        #pragma unroll
        for (int r = 0; r < 4; r++)
          C[(size_t)(mb + r) * N + n] = f2b(acc[i][j][r]);
      }
    }
  }
}

// ---------------------------------------------------------------------------
// C(f32) = xpos( A(f32) @ B^T ) split-bf16 (3-term). Dbuf BK=32, swizzled
// LDS, XCD remap. xpos fused in epilogue (partner col = lane^1).
// QG=1: A-row gather r -> (r>>6)*4096 + (r&63), position = row & 63.
// ---------------------------------------------------------------------------
template<int QG>
__global__ __launch_bounds__(256, 2)
void gemm_split(const float* __restrict__ A, const unsigned short* __restrict__ Bh,
                const unsigned short* __restrict__ Bl, float* __restrict__ C,
                int M, int N, int K)
{
  __shared__ __align__(16) short Ash[2][128*32];
  __shared__ __align__(16) short Asl[2][128*32];
  __shared__ __align__(16) short Bsh[2][128*32];
  __shared__ __align__(16) short Bsl[2][128*32];
  const int t    = threadIdx.x;
  const int lane = t & 63;
  const int w    = t >> 6, wm = w >> 1, wn = w & 1;
  const int l15  = lane & 15, kg = lane >> 4;
  const int sxr  = ((l15 >> 1) & 3) * 8;
  long bmi, bni; tile_remap(bmi, bni);
  const long bm = bmi * 128, bn = bni * 128;

  size_t bgo[2]; int bls[2];
  #pragma unroll
  for (int u = 0; u < 2; u++){
    const int cl  = u*256 + t;
    const int row = cl >> 2, cr = cl & 3;
    const int csrc = cr ^ ((row >> 1) & 3);
    bgo[u] = (size_t)(bn + row) * K + csrc*8;
    bls[u] = cl * 8;
  }
  const int arow = t >> 1, acolb = (t & 1) * 16;
  long ar = bm + arow;
  if (QG) ar = (ar >> 6) * 4096 + (ar & 63);
  const float* pa = A + ar * (size_t)K + acolb;
  const int aw0 = arow*32 + ((((t&1)*2    ) ^ ((t>>2)&3)))*8;
  const int aw1 = arow*32 + ((((t&1)*2 + 1) ^ ((t>>2)&3)))*8;

  floatx4 acc[4][4] = {};
  floatx4 sta[4], stb[4];

  // prologue: stage tile 0 into buf 0; prefetch A(1).
  #pragma unroll
  for (int u = 0; u < 2; u++){
    lds_dma16(Bh + bgo[u], &Bsh[0][bls[u]]);
    lds_dma16(Bl + bgo[u], &Bsl[0][bls[u]]);
  }
  #pragma unroll
  for (int u = 0; u < 4; u++) sta[u] = *(const floatx4*)(pa + u*4);
  {
    short8 h0, h1, l0, l1;
    #pragma unroll
    for (int j = 0; j < 8; j++){
      float x0 = sta[j>>2][j&3], x1 = sta[2 + (j>>2)][j&3];
      unsigned short hb0 = f2b(x0), hb1 = f2b(x1);
      h0[j] = (short)hb0; l0[j] = (short)f2b(x0 - b2f(hb0));
      h1[j] = (short)hb1; l1[j] = (short)f2b(x1 - b2f(hb1));
    }
    *(short8*)&Ash[0][aw0] = h0; *(short8*)&Ash[0][aw1] = h1;
    *(short8*)&Asl[0][aw0] = l0; *(short8*)&Asl[0][aw1] = l1;
  }
  #pragma unroll
  for (int u = 0; u < 4; u++) sta[u] = *(const floatx4*)(pa + 32 + u*4);
  __syncthreads();

  const int NT = K >> 5;
  int o = 0;
  for (int kt = 0; kt < NT; ++kt){
    if (kt + 1 < NT){
      short8 h0, h1, l0, l1;
      #pragma unroll
      for (int j = 0; j < 8; j++){
        float x0 = sta[j>>2][j&3], x1 = sta[2 + (j>>2)][j&3];
        unsigned short hb0 = f2b(x0), hb1 = f2b(x1);
        h0[j] = (short)hb0; l0[j] = (short)f2b(x0 - b2f(hb0));
        h1[j] = (short)hb1; l1[j] = (short)f2b(x1 - b2f(hb1));
      }
      *(short8*)&Ash[o^1][aw0] = h0; *(short8*)&Ash[o^1][aw1] = h1;
      *(short8*)&Asl[o^1][aw0] = l0; *(short8*)&Asl[o^1][aw1] = l1;
      const int k1 = (kt + 1) << 5;
      #pragma unroll
      for (int u = 0; u < 2; u++){
        lds_dma16(Bh + bgo[u] + k1, &Bsh[o^1][bls[u]]);
        lds_dma16(Bl + bgo[u] + k1, &Bsl[o^1][bls[u]]);
      }
      const int k2 = ((kt + 2 < NT) ? (kt + 2) : kt) << 5;
      #pragma unroll
      for (int u = 0; u < 4; u++) stb[u] = *(const floatx4*)(pa + k2 + u*4);
    }
    short8 afh[4], afl[4], bvh[4], bvl[4];
    #pragma unroll
    for (int i = 0; i < 4; i++){
      const int ra = (wm*64 + i*16 + l15)*32 + ((kg*8) ^ sxr);
      const int rb = (wn*64 + i*16 + l15)*32 + ((kg*8) ^ sxr);
      afh[i] = *(const short8*)&Ash[o][ra];
      afl[i] = *(const short8*)&Asl[o][ra];
      bvh[i] = *(const short8*)&Bsh[o][rb];
      bvl[i] = *(const short8*)&Bsl[o][rb];
    }
    #pragma unroll
    for (int i = 0; i < 4; i++)
      #pragma unroll
      for (int j = 0; j < 4; j++){
        acc[i][j] = mfma_bf16(afh[i], bvh[j], acc[i][j]);
        acc[i][j] = mfma_bf16(afh[i], bvl[j], acc[i][j]);
        acc[i][j] = mfma_bf16(afl[i], bvh[j], acc[i][j]);
      }
    __syncthreads();
    o ^= 1;
    #pragma unroll
    for (int u = 0; u < 4; u++) sta[u] = stb[u];
  }

  // fused xpos epilogue. col pairs (2ip, 2ip+1) sit in lanes (l, l^1).
  const int smask = QG ? 63 : 4095;
  #pragma unroll
  for (int j = 0; j < 4; j++){
    const long n  = bn + wn*64 + j*16 + l15;
    const int  ip = (int)(n >> 1);
    const float lsv  = __logf((2.0f*ip + 409.6f) * (1.0f/1433.6f));
    const float invf = __expf(-(float)ip * (9.2103403720f/512.0f));  // 10000^(-ip/512)
    const float sgn  = (n & 1) ? 1.0f : -1.0f;
    #pragma unroll
    for (int i = 0; i < 4; i++){
      const long mb = bm + wm*64 + i*16 + kg*4;
      #pragma unroll
      for (int r = 0; r < 4; r++){
        float x = acc[i][j][r];
        float p = __shfl_xor(x, 1);
        const float fs = (float)((int)((mb + r) & smask));
        const float scale = __expf(lsv * fs * (1.0f/512.0f));
        float sn, cs;
        __sincosf(fs * invf, &sn, &cs);
        sn *= scale; cs *= scale;
        C[(size_t)(mb + r) * N + n] = x*cs + sgn*(p*sn);
      }
    }
  }
}

// ---------------------------------------------------------------------------
// Split-precision projection: P[b*2][e][d'] += sum_s wxw[e,s]*X[b][s,d'].
// ---------------------------------------------------------------------------
__global__ __launch_bounds__(256, 2)
void proj_split(const float* __restrict__ X0, const unsigned short* __restrict__ wxh,
                const unsigned short* __restrict__ wxl, float* __restrict__ P)
{
  __shared__ __align__(16) short Wsh[64*32];
  __shared__ __align__(16) short Wsl[64*32];
  __shared__ __align__(16) short Xth[64*40];
  __shared__ __align__(16) short Xtl[64*40];
  const int t = threadIdx.x, w = t >> 6, lane = t & 63;
  const int l15 = lane & 15, kg = lane >> 4;
  const int d0 = blockIdx.x * 64;
  const int b  = blockIdx.y;
  const float* X = X0 + (size_t)b * 4096 * 1024;
  const int s0 = blockIdx.z * 512;
  const int ssr = t >> 3, ddr = (t & 7) * 8;
  floatx4 acc[4] = {};

  for (int kk = 0; kk < 512; kk += 32){
    const int s = s0 + kk;
    floatx4 x0 = *(const floatx4*)&X[(size_t)(s + ssr) * 1024 + d0 + ddr];
    floatx4 x1 = *(const floatx4*)&X[(size_t)(s + ssr) * 1024 + d0 + ddr + 4];
    __syncthreads();
    lds_dma16(&wxh[(size_t)(t >> 2) * 4096 + s + (t & 3) * 8], &Wsh[t*8]);
    lds_dma16(&wxl[(size_t)(t >> 2) * 4096 + s + (t & 3) * 8], &Wsl[t*8]);
    float xv[8] = {x0[0],x0[1],x0[2],x0[3],x1[0],x1[1],x1[2],x1[3]};
    #pragma unroll
    for (int j = 0; j < 8; j++){
      unsigned short hb = f2b(xv[j]);
      Xth[(ddr + j) * 40 + ssr] = (short)hb;
      Xtl[(ddr + j) * 40 + ssr] = (short)f2b(xv[j] - b2f(hb));
    }
    __syncthreads();
    short8 afh = *(const short8*)&Wsh[(w*16 + l15)*32 + kg*8];
    short8 afl = *(const short8*)&Wsl[(w*16 + l15)*32 + kg*8];
    #pragma unroll
    for (int j = 0; j < 4; j++){
      short8 bvh = *(const short8*)&Xth[(j*16 + l15)*40 + kg*8];
      short8 bvl = *(const short8*)&Xtl[(j*16 + l15)*40 + kg*8];
      acc[j] = mfma_bf16(afh, bvh, acc[j]);
      acc[j] = mfma_bf16(afh, bvl, acc[j]);
      acc[j] = mfma_bf16(afl, bvh, acc[j]);
    }
  }
  float* Pb = P + (size_t)(b*2) * 65536;
  #pragma unroll
  for (int j = 0; j < 4; j++)
    #pragma unroll
    for (int r = 0; r < 4; r++)
      atomicAdd(&Pb[(w*16 + kg*4 + r) * 1024 + d0 + j*16 + l15], acc[j][r]);
}

// ---------------------------------------------------------------------------
// bf16 projection for V: P[b*2+1][e][d'] += sum_s wxw_h[e,s]*X[b][s,d']
// ---------------------------------------------------------------------------
__global__ __launch_bounds__(256, 2)
void proj_bf16(const unsigned short* __restrict__ X0, const unsigned short* __restrict__ wxw_bf,
               float* __restrict__ P)
{
  __shared__ __align__(16) short Ws[64*32];
  __shared__ __align__(16) short Xt[64*40];
  const int t = threadIdx.x, w = t >> 6, lane = t & 63;
  const int l15 = lane & 15, kg = lane >> 4;
  const int d0 = blockIdx.x * 64;
  const int b  = blockIdx.y;
  const unsigned short* X = X0 + (size_t)b * 4096 * 1024;
  const int s0 = blockIdx.z * 512;
  const int ssr = t >> 3, ddr = (t & 7) * 8;
  floatx4 acc[4] = {};

  for (int kk = 0; kk < 512; kk += 32){
    const int s = s0 + kk;
    short8 xv = *(const short8*)&X[(size_t)(s + ssr) * 1024 + d0 + ddr];
    __syncthreads();
    lds_dma16(&wxw_bf[(size_t)(t >> 2) * 4096 + s + (t & 3) * 8], &Ws[t*8]);
    #pragma unroll
    for (int j = 0; j < 8; j++) Xt[(ddr + j) * 40 + ssr] = xv[j];
    __syncthreads();
    short8 af = *(const short8*)&Ws[(w*16 + l15)*32 + kg*8];
    #pragma unroll
    for (int j = 0; j < 4; j++){
      short8 bv = *(const short8*)&Xt[(j*16 + l15)*40 + kg*8];
      acc[j] = mfma_bf16(af, bv, acc[j]);
    }
  }
  float* Pb = P + (size_t)(b*2 + 1) * 65536;
  #pragma unroll
  for (int j = 0; j < 4; j++)
    #pragma unroll
    for (int r = 0; r < 4; r++)
      atomicAdd(&Pb[(w*16 + kg*4 + r) * 1024 + d0 + j*16 + l15], acc[j][r]);
}

// ---------------------------------------------------------------------------
// Per (b,h) attention + group norm. 256 threads: wave w owns e-quarter for
// scores and g-quarter for outputs; scores round-trip through LDS.
// Masked score entries are literal ZEROS (matches reference softmax).
// ---------------------------------------------------------------------------
__global__ __launch_bounds__(256)
void attn_kernel(const float* __restrict__ P, const float* __restrict__ Qx,
                 const float* __restrict__ wxb,
                 const float* __restrict__ gnw, const float* __restrict__ gnb,
                 float* __restrict__ zs, float* __restrict__ zc)
{
  __shared__ __align__(16) float kps[64*64];   // [e][d]
  __shared__ __align__(16) float vps[64*64];   // [e][f]
  __shared__ __align__(16) float scs[64*65];   // [e][s], stride 65
  __shared__ float pm[256];
  __shared__ float ym[64];
  const int t = threadIdx.x;
  const int w = t >> 6, s = t & 63;
  const int b = blockIdx.x >> 4, h = blockIdx.x & 15;
  const float* Pk = P + (size_t)(2*b) * 65536 + h*64;
  const float* Pv = Pk + 65536;

  {
    const int e = t >> 2, c = (t & 3) * 16;
    const float wb = wxb[e];
    #pragma unroll
    for (int j = 0; j < 4; j++){
      floatx4 kv = *(const floatx4*)&Pk[(size_t)e*1024 + c + 4*j];
      floatx4 vv = *(const floatx4*)&Pv[(size_t)e*1024 + c + 4*j];
      kv.x += wb; kv.y += wb; kv.z += wb; kv.w += wb;
      vv.x += wb; vv.y += wb; vv.z += wb; vv.w += wb;
      *(floatx4*)&kps[e*64 + c + 4*j] = kv;
      *(floatx4*)&vps[e*64 + c + 4*j] = vv;
    }
  }
  __syncthreads();

  float qf[64];
  const floatx4* q4 = (const floatx4*)(Qx + (size_t)(b*64 + s)*1024 + h*64);
  #pragma unroll
  for (int i = 0; i < 16; i++){
    floatx4 qq = q4[i];
    qf[4*i] = qq.x; qf[4*i+1] = qq.y; qf[4*i+2] = qq.z; qf[4*i+3] = qq.w;
  }

  #pragma unroll
  for (int eo = 0; eo < 16; eo++){
    const int e = w*16 + eo;
    const floatx4* kp4 = (const floatx4*)&kps[e*64];
    float dot = 0.f;
    #pragma unroll
    for (int d = 0; d < 16; d++){
      floatx4 kv = kp4[d];
      dot += qf[4*d]*kv.x + qf[4*d+1]*kv.y + qf[4*d+2]*kv.z + qf[4*d+3]*kv.w;
    }
    scs[e*65 + s] = dot;
  }
  {
    float am = 0.f;
    #pragma unroll
    for (int eo = 0; eo < 16; eo++) am += vps[(w*16 + eo)*64 + s];
    pm[t] = am;
  }
  __syncthreads();

  const float lg = -3.4657359028f - 0.1848392483f * (float)h;
  const float gamma = 1.0f - __expf(lg);
  float sc[64];
  #pragma unroll
  for (int e = 0; e < 64; e++) sc[e] = scs[e*65 + s];
  float dec = 1.0f;
  #pragma unroll
  for (int e = 0; e < 64; e++){
    bool on = (e >= s);
    sc[e] = on ? sc[e]*dec : 0.0f;
    if (on) dec *= gamma;
  }
  float mx = -1e30f;
  #pragma unroll
  for (int e = 0; e < 64; e++) mx = fmaxf(mx, sc[e]);
  float Z = 0.f;
  #pragma unroll
  for (int e = 0; e < 64; e++){ sc[e] = __expf(sc[e] - mx); Z += sc[e]; }
  const float rz = 1.0f / Z;

  #pragma unroll
  for (int go = 0; go < 4; go++){
    const int g = w*4 + go;
    floatx4 y = {0.f,0.f,0.f,0.f};
    #pragma unroll
    for (int e = 0; e < 64; e++){
      floatx4 vv = *(const floatx4*)&vps[e*64 + g*4];
      y += sc[e] * vv;
    }
    y *= rz;
    float mu = (y.x + y.y + y.z + y.w) * 0.25f;
    float a0 = y.x-mu, a1 = y.y-mu, a2 = y.z-mu, a3 = y.w-mu;
    float inv = rsqrtf((a0*a0 + a1*a1 + a2*a2 + a3*a3)*0.25f + 1e-5f);
    floatx4 o;
    o.x = a0*inv*gnw[g*4+0] + gnb[g*4+0];
    o.y = a1*inv*gnw[g*4+1] + gnb[g*4+1];
    o.z = a2*inv*gnw[g*4+2] + gnb[g*4+2];
    o.w = a3*inv*gnw[g*4+3] + gnb[g*4+3];
    *(floatx4*)&zs[(size_t)(b*64 + s)*1024 + h*64 + g*4] = o;
  }

  if (w == 0)
    ym[s] = (pm[s] + pm[64+s] + pm[128+s] + pm[192+s]) * (1.0f/64.0f);
  __syncthreads();
  if (t < 16){
    float a0 = ym[t*4], a1 = ym[t*4+1], a2 = ym[t*4+2], a3 = ym[t*4+3];
    float mu = (a0+a1+a2+a3)*0.25f;
    a0 -= mu; a1 -= mu; a2 -= mu; a3 -= mu;
    float inv = rsqrtf((a0*a0+a1*a1+a2*a2+a3*a3)*0.25f + 1e-5f);
    zc[(size_t)b*1024 + h*64 + t*4+0] = a0*inv*gnw[t*4+0] + gnb[t*4+0];
    zc[(size_t)b*1024 + h*64 + t*4+1] = a1*inv*gnw[t*4+1] + gnb[t*4+1];
    zc[(size_t)b*1024 + h*64 + t*4+2] = a2*inv*gnw[t*4+2] + gnb[t*4+2];
    zc[(size_t)b*1024 + h*64 + t*4+3] = a3*inv*gnw[t*4+3] + gnb[t*4+3];
  }
}

// ---------------------------------------------------------------------------
// C(f32) = A(bf16) @ B(bf16)^T — final GEMM. Dbuf BK=32, both operands DMA,
// swizzled LDS, XCD remap, 3 blocks/CU.
// ---------------------------------------------------------------------------
__global__ __launch_bounds__(256, 3)
void gemm_bt(const unsigned short* __restrict__ A, const unsigned short* __restrict__ Bw,
             float* __restrict__ C, int M, int N, int K)
{
  __shared__ __align__(16) short As[2][128*32];
  __shared__ __align__(16) short Bs[2][128*32];
  const int t    = threadIdx.x;
  const int lane = t & 63;
  const int w    = t >> 6, wm = w >> 1, wn = w & 1;
  const int l15  = lane & 15, kg = lane >> 4;
  const int sxr  = ((l15 >> 1) & 3) * 8;
  long bmi, bni; tile_remap(bmi, bni);
  const long bm = bmi * 128, bn = bni * 128;

  size_t ago[2], bgo[2]; int bls[2];
  #pragma unroll
  for (int u = 0; u < 2; u++){
    const int cl  = u*256 + t;
    const int row = cl >> 2, cr = cl & 3;
    const int csrc = cr ^ ((row >> 1) & 3);
    ago[u] = (size_t)(bm + row) * K + csrc*8;
    bgo[u] = (size_t)(bn + row) * K + csrc*8;
    bls[u] = cl * 8;
  }

  floatx4 acc[4][4] = {};

  // prologue: stage tile 0 into buf 0.
  #pragma unroll
  for (int u = 0; u < 2; u++){
    lds_dma16(A  + ago[u], &As[0][bls[u]]);
    lds_dma16(Bw + bgo[u], &Bs[0][bls[u]]);
  }
  __syncthreads();

  const int NT = K >> 5;
  int o = 0;
  for (int kt = 0; kt < NT; ++kt){
    if (kt + 1 < NT){
      const int k1 = (kt + 1) << 5;
      #pragma unroll
      for (int u = 0; u < 2; u++){
        lds_dma16(A  + ago[u] + k1, &As[o^1][bls[u]]);
        lds_dma16(Bw + bgo[u] + k1, &Bs[o^1][bls[u]]);
      }
    }
    short8 af[4], bv[4];
    #pragma unroll
    for (int i = 0; i < 4; i++){
      af[i] = *(const short8*)&As[o][(wm*64 + i*16 + l15)*32 + ((kg*8) ^ sxr)];
      bv[i] = *(const short8*)&Bs[o][(wn*64 + i*16 + l15)*32 + ((kg*8) ^ sxr)];
    }
    #pragma unroll
    for (int i = 0; i < 4; i++)
      #pragma unroll
      for (int j = 0; j < 4; j++)
        acc[i][j] = mfma_bf16(af[i], bv[j], acc[i][j]);
    __syncthreads();
    o ^= 1;
  }

  #pragma unroll
  for (int i = 0; i < 4; i++){
    const long mb = bm + wm*64 + i*16 + kg*4;
    #pragma unroll
    for (int j = 0; j < 4; j++){
      const long n = bn + wn*64 + j*16 + l15;
      #pragma unroll
      for (int r = 0; r < 4; r++)
        C[(size_t)(mb + r) * N + n] = acc[i][j][r];
    }
  }
}

// ---------------------------------------------------------------------------
extern "C" void kernel_launch(void* const* d_in, const int* in_sizes, int n_in,
                              void* d_out, int out_size, void* d_ws, size_t ws_size,
                              hipStream_t stream)
{
  const float* q   = (const float*)d_in[0];
  const float* k   = (const float*)d_in[1];
  const float* v   = (const float*)d_in[2];
  const float* wq  = (const float*)d_in[3];
  const float* wk  = (const float*)d_in[4];
  const float* wv  = (const float*)d_in[5];
  const float* wo  = (const float*)d_in[6];
  const float* wg  = (const float*)d_in[7];
  const float* wxw = (const float*)d_in[8];
  const float* wxb = (const float*)d_in[9];
  const float* gnw = (const float*)d_in[10];
  const float* gnb = (const float*)d_in[11];

  // ws layout (47.2 MB). d_out (f32, 64 MB) doubles as Kx f32 scratch.
  char* ws = (char*)d_ws;
  unsigned short* A0   = (unsigned short*)(ws);             // 32 MB: Vx bf16 -> Agate bf16
  unsigned short* wh   = (unsigned short*)(ws + 33554432);  // 2 MB: wk_h -> wq_h
  unsigned short* wl   = (unsigned short*)(ws + 35651584);  // 2 MB: wk_l -> wq_l
  unsigned short* wAbf = (unsigned short*)(ws + 37748736);  // 2 MB: wv -> wo
  unsigned short* wgbf = (unsigned short*)(ws + 39845888);  // 2 MB
  unsigned short* wxh  = (unsigned short*)(ws + 41943040);  // 512 KB
  unsigned short* wxl  = (unsigned short*)(ws + 42467328);  // 512 KB
  float*          P    = (float*)(ws + 42991616);           // 2 MB
  float*          zs   = (float*)(ws + 45088768);           // 1 MB
  float*          zc   = (float*)(ws + 46137344);           // 16 KB
  float*          Qx   = (float*)(ws + 46153728);           // 1 MB
  float*          Kx   = (float*)d_out;                     // 64 MB f32 scratch

  const int M = 16384, N = 1024, K = 1024;
  dim3 blk(256);

  // weight prep
  cvt_split<<<512, blk, 0, stream>>>(wk, wh, wl, 131072);
  cvt_split<<<128, blk, 0, stream>>>(wxw, wxh, wxl, 32768);
  cvt_kernel<<<512, blk, 0, stream>>>(wv, wAbf, 131072);
  cvt_kernel<<<512, blk, 0, stream>>>(wg, wgbf, 131072);
  hipMemsetAsync(P, 0, 2097152, stream);

  // K path: k @ wk^T -> Kx f32 (xpos fused in epilogue), then proj
  gemm_split<0><<<dim3(8,128), blk, 0, stream>>>(k, wh, wl, Kx, M, N, K);
  proj_split<<<dim3(16,4,8), blk, 0, stream>>>(Kx, wxh, wxl, P);

  // V path: v @ wv^T -> A0 bf16, proj
  gemm_af32<0><<<dim3(8,128), blk, 0, stream>>>(v, wAbf, A0, M, N, K, nullptr, nullptr);
  proj_bf16<<<dim3(16,4,8), blk, 0, stream>>>(A0, wxh, P);
  cvt_kernel<<<512, blk, 0, stream>>>(wo, wAbf, 131072);   // wv dead -> wo

  // Q path: gather 64 rows/batch, xpos fused, attention
  cvt_split<<<512, blk, 0, stream>>>(wq, wh, wl, 131072);  // wk dead -> wq
  gemm_split<1><<<dim3(8,2), blk, 0, stream>>>(q, wh, wl, Qx, 256, N, K);
  attn_kernel<<<64, 256, 0, stream>>>(P, Qx, wxb, gnw, gnb, zs, zc);

  // Gate path: G = silu((q @ wg^T) * z) fused in epilogue -> A0, final GEMM
  gemm_af32<1><<<dim3(8,128), blk, 0, stream>>>(q, wgbf, A0, M, N, K, zs, zc);
  gemm_bt<<<dim3(8,128), blk, 0, stream>>>(A0, wAbf, (float*)d_out, M, N, K);
}

// Round 7
// 596.068 us; speedup vs baseline: 1.0642x; 1.0642x over previous
//
#include <hip/hip_runtime.h>
#include <hip/hip_bf16.h>

#define DEVI __device__ __forceinline__

typedef __attribute__((ext_vector_type(8))) short  short8;
typedef __attribute__((ext_vector_type(4))) float  floatx4;
typedef __attribute__((ext_vector_type(8))) __bf16 bf16x8;

DEVI float b2f(unsigned short u){ union{unsigned int i; float f;} x; x.i=((unsigned int)u)<<16; return x.f; }
DEVI unsigned short f2b(float f){
  union{float ff; unsigned int i;} x; x.ff=f;
  unsigned int r = x.i + 0x7fffu + ((x.i>>16)&1u);
  return (unsigned short)(r>>16);
}

DEVI void lds_dma16(const void* g, void* l){
  __builtin_amdgcn_global_load_lds((const __attribute__((address_space(1))) void*)g,
                                   (__attribute__((address_space(3))) void*)l, 16, 0, 0);
}

DEVI floatx4 mfma_bf16(short8 a, short8 b, floatx4 c){
  return __builtin_amdgcn_mfma_f32_16x16x32_bf16(
      __builtin_bit_cast(bf16x8, a), __builtin_bit_cast(bf16x8, b), c, 0, 0, 0);
}

// XCD-chunked tile remap (T1). Verified R4: FETCH 266MB -> 65.6MB.
DEVI void tile_remap(long& bmi, long& bni){
  const int bx = blockIdx.x, by = blockIdx.y;
  if (gridDim.y == 128){
    bni = (long)(by & 7);
    bmi = (long)((bx << 4) + (by >> 3));
  } else {
    bni = bx; bmi = by;
  }
}

// BK=64 2-barrier K-loop (R4-verified geometry) with READ-THEN-STAGE reorder:
//   bar1: stage(kt) landed (DMAs flew under previous MFMA phase)
//   ds_write A(kt) from regs; read ALL B fragments
//   bar2: A visible to readers, B buffer free
//   issue B-DMA(kt+1) + A-reg loads(kt+1)  -> fly under MFMAs
//   A-frag reads + MFMAs
// LDS swizzle (both-sides XOR, rule 21) as verified in R3-R5: 0 conflicts.

// ---------------------------------------------------------------------------
// f32 -> bf16 (single) elementwise
// ---------------------------------------------------------------------------
__global__ void cvt_kernel(const float* __restrict__ src, unsigned short* __restrict__ dst, int n8)
{
  const int i = blockIdx.x * 256 + threadIdx.x;
  if (i >= n8) return;
  floatx4 a = ((const floatx4*)src)[2*(size_t)i];
  floatx4 b = ((const floatx4*)src)[2*(size_t)i + 1];
  short8 o;
  o[0]=(short)f2b(a[0]); o[1]=(short)f2b(a[1]); o[2]=(short)f2b(a[2]); o[3]=(short)f2b(a[3]);
  o[4]=(short)f2b(b[0]); o[5]=(short)f2b(b[1]); o[6]=(short)f2b(b[2]); o[7]=(short)f2b(b[3]);
  *(short8*)&dst[(size_t)i*8] = o;
}

// ---------------------------------------------------------------------------
// f32 -> (hi, lo) bf16 split: hi = rne(x), lo = rne(x - hi).
// ---------------------------------------------------------------------------
__global__ void cvt_split(const float* __restrict__ src, unsigned short* __restrict__ dh,
                          unsigned short* __restrict__ dl, int n8)
{
  const int i = blockIdx.x * 256 + threadIdx.x;
  if (i >= n8) return;
  floatx4 a = ((const floatx4*)src)[2*(size_t)i];
  floatx4 b = ((const floatx4*)src)[2*(size_t)i + 1];
  short8 h, l;
  #pragma unroll
  for (int j = 0; j < 8; j++){
    float x = (j < 4) ? a[j] : b[j-4];
    unsigned short hb = f2b(x);
    h[j] = (short)hb;
    l[j] = (short)f2b(x - b2f(hb));
  }
  *(short8*)&dh[(size_t)i*8] = h;
  *(short8*)&dl[(size_t)i*8] = l;
}

// ---------------------------------------------------------------------------
// C(bf16) = A(f32) @ Bw(bf16)^T.  BK=64, swizzled LDS, XCD remap, pipelined
// stage-after-read, 3 blocks/CU. GATE=1: fused z*silu epilogue.
// ---------------------------------------------------------------------------
template<int GATE>
__global__ __launch_bounds__(256, 3)
void gemm_af32(const float* __restrict__ A, const unsigned short* __restrict__ Bw,
               unsigned short* __restrict__ C, int M, int N, int K,
               const float* __restrict__ zs, const float* __restrict__ zc)
{
  __shared__ __align__(16) short As[128*64];
  __shared__ __align__(16) short Bs[128*64];
  const int t    = threadIdx.x;
  const int lane = t & 63;
  const int w    = t >> 6, wm = w >> 1, wn = w & 1;
  const int l15  = lane & 15, kg = lane >> 4;
  const int sx   = (l15 & 7) * 8;
  long bmi, bni; tile_remap(bmi, bni);
  const long bm = bmi * 128, bn = bni * 128;

  const int sr = t >> 3, sc8 = (t & 7) * 8;
  const int scx = sc8 ^ ((sr & 7) * 8);
  const unsigned short* pb[4];
  const float* pa[4];
  short *lb[4], *la[4];
  #pragma unroll
  for (int u = 0; u < 4; u++){
    pb[u] = Bw + (bn + sr + u*32) * (size_t)K + scx; // inverse-swizzled source
    pa[u] = A  + (bm + sr + u*32) * (size_t)K + sc8; // plain source
    lb[u] = &Bs[(sr + u*32)*64 + sc8];               // linear DMA dest (t*16B)
    la[u] = &As[(sr + u*32)*64 + scx];               // swizzled ds_write dest
  }

  floatx4 acc[4][4] = {};
  floatx4 cur[8];
  #pragma unroll
  for (int u = 0; u < 4; u++){
    cur[2*u]   = *(const floatx4*)(pa[u]);
    cur[2*u+1] = *(const floatx4*)(pa[u] + 4);
  }
  #pragma unroll
  for (int u = 0; u < 4; u++) lds_dma16(pb[u], lb[u]);  // B(0)

  const int NT = K >> 6;
  for (int kt = 0; kt < NT; ++kt){
    __syncthreads();                        // bar1: stage(kt) landed
    #pragma unroll
    for (int u = 0; u < 4; u++){            // ds_write A(kt) from cur
      short8 h;
      #pragma unroll
      for (int j = 0; j < 8; j++){
        float x = (j < 4) ? cur[2*u][j] : cur[2*u+1][j-4];
        h[j] = (short)f2b(x);
      }
      *(short8*)la[u] = h;
    }
    short8 bv[2][4];                        // read ALL B frags before bar2
    #pragma unroll
    for (int ks = 0; ks < 2; ks++)
      #pragma unroll
      for (int i = 0; i < 4; i++)
        bv[ks][i] = *(const short8*)&Bs[(wn*64 + i*16 + l15)*64 + ((ks*32 + kg*8) ^ sx)];
    __syncthreads();                        // bar2: A visible, B buffer free
    const int kn = (kt + 1 < NT) ? ((kt + 1) << 6) : 0;
    if (kt + 1 < NT){
      #pragma unroll
      for (int u = 0; u < 4; u++) lds_dma16(pb[u] + kn, lb[u]);
    }
    #pragma unroll
    for (int u = 0; u < 4; u++){            // cur <- A(kt+1), flies under MFMA
      cur[2*u]   = *(const floatx4*)(pa[u] + kn);
      cur[2*u+1] = *(const floatx4*)(pa[u] + kn + 4);
    }
    __builtin_amdgcn_sched_barrier(0);      // pin issue order: loads before MFMAs
    #pragma unroll
    for (int ks = 0; ks < 2; ks++){
      short8 af[4];
      #pragma unroll
      for (int i = 0; i < 4; i++)
        af[i] = *(const short8*)&As[(wm*64 + i*16 + l15)*64 + ((ks*32 + kg*8) ^ sx)];
      #pragma unroll
      for (int i = 0; i < 4; i++)
        #pragma unroll
        for (int j = 0; j < 4; j++)
          acc[i][j] = mfma_bf16(af[i], bv[ks][j], acc[i][j]);
    }
  }

  if (GATE){
    #pragma unroll
    for (int i = 0; i < 4; i++){
      const long mb = bm + wm*64 + i*16 + kg*4;
      #pragma unroll
      for (int r = 0; r < 4; r++){
        const long row = mb + r;
        const int  ss  = (int)(row & 4095);
        const long bb  = row >> 12;
        const float* zr = (ss < 64) ? (zs + (((size_t)(bb*64 + ss)) << 10))
                                    : (zc + ((size_t)bb << 10));
        #pragma unroll
        for (int j = 0; j < 4; j++){
          const long n = bn + wn*64 + j*16 + l15;
          float g = acc[i][j][r] * zr[n];
          float sig = 1.0f / (1.0f + __expf(-g));
          C[(size_t)row * N + n] = f2b(g * sig);
        }
      }
    }
  } else {
    #pragma unroll
    for (int i = 0; i < 4; i++){
      const long mb = bm + wm*64 + i*16 + kg*4;
      #pragma unroll
      for (int j = 0; j < 4; j++){
        const long n = bn + wn*64 + j*16 + l15;
        #pragma unroll
        for (int r = 0; r < 4; r++)
          C[(size_t)(mb + r) * N + n] = f2b(acc[i][j][r]);
      }
    }
  }
}

// ---------------------------------------------------------------------------
// C(f32) = xpos( A(f32) @ B^T ) split-bf16 (3-term). BK=64, swizzled LDS,
// XCD remap, pipelined stage-after-read. xpos fused (partner col = lane^1).
// QG=1: A-row gather r -> (r>>6)*4096 + (r&63), position = row & 63.
// ---------------------------------------------------------------------------
template<int QG>
__global__ __launch_bounds__(256, 2)
void gemm_split(const float* __restrict__ A, const unsigned short* __restrict__ Bh,
                const unsigned short* __restrict__ Bl, float* __restrict__ C,
                int M, int N, int K)
{
  __shared__ __align__(16) short Ash[128*64];
  __shared__ __align__(16) short Asl[128*64];
  __shared__ __align__(16) short Bsh[128*64];
  __shared__ __align__(16) short Bsl[128*64];
  const int t    = threadIdx.x;
  const int lane = t & 63;
  const int w    = t >> 6, wm = w >> 1, wn = w & 1;
  const int l15  = lane & 15, kg = lane >> 4;
  const int sx   = (l15 & 7) * 8;
  long bmi, bni; tile_remap(bmi, bni);
  const long bm = bmi * 128, bn = bni * 128;

  const int sr = t >> 3, sc8 = (t & 7) * 8;
  const int scx = sc8 ^ ((sr & 7) * 8);
  const unsigned short *pbh[4], *pbl[4];
  const float* pa[4];
  short *lbh[4], *lbl[4], *lah[4], *lal[4];
  #pragma unroll
  for (int u = 0; u < 4; u++){
    pbh[u] = Bh + (bn + sr + u*32) * (size_t)K + scx;
    pbl[u] = Bl + (bn + sr + u*32) * (size_t)K + scx;
    long ar = bm + sr + u*32;
    if (QG) ar = (ar >> 6) * 4096 + (ar & 63);
    pa[u]  = A + ar * (size_t)K + sc8;
    lbh[u] = &Bsh[(sr + u*32)*64 + sc8];
    lbl[u] = &Bsl[(sr + u*32)*64 + sc8];
    lah[u] = &Ash[(sr + u*32)*64 + scx];
    lal[u] = &Asl[(sr + u*32)*64 + scx];
  }

  floatx4 acc[4][4] = {};
  floatx4 cur[8];
  #pragma unroll
  for (int u = 0; u < 4; u++){
    cur[2*u]   = *(const floatx4*)(pa[u]);
    cur[2*u+1] = *(const floatx4*)(pa[u] + 4);
  }
  #pragma unroll
  for (int u = 0; u < 4; u++){
    lds_dma16(pbh[u], lbh[u]);
    lds_dma16(pbl[u], lbl[u]);
  }

  const int NT = K >> 6;
  for (int kt = 0; kt < NT; ++kt){
    __syncthreads();                        // bar1
    #pragma unroll
    for (int u = 0; u < 4; u++){            // ds_write A(kt) hi/lo from cur
      short8 h, l;
      #pragma unroll
      for (int j = 0; j < 8; j++){
        float x = (j < 4) ? cur[2*u][j] : cur[2*u+1][j-4];
        unsigned short hb = f2b(x);
        h[j] = (short)hb;
        l[j] = (short)f2b(x - b2f(hb));
      }
      *(short8*)lah[u] = h;
      *(short8*)lal[u] = l;
    }
    short8 bvh[2][4], bvl[2][4];            // all B frags before bar2
    #pragma unroll
    for (int ks = 0; ks < 2; ks++)
      #pragma unroll
      for (int i = 0; i < 4; i++){
        const int rb = (wn*64 + i*16 + l15)*64 + ((ks*32 + kg*8) ^ sx);
        bvh[ks][i] = *(const short8*)&Bsh[rb];
        bvl[ks][i] = *(const short8*)&Bsl[rb];
      }
    __syncthreads();                        // bar2
    const int kn = (kt + 1 < NT) ? ((kt + 1) << 6) : 0;
    if (kt + 1 < NT){
      #pragma unroll
      for (int u = 0; u < 4; u++){
        lds_dma16(pbh[u] + kn, lbh[u]);
        lds_dma16(pbl[u] + kn, lbl[u]);
      }
    }
    #pragma unroll
    for (int u = 0; u < 4; u++){
      cur[2*u]   = *(const floatx4*)(pa[u] + kn);
      cur[2*u+1] = *(const floatx4*)(pa[u] + kn + 4);
    }
    __builtin_amdgcn_sched_barrier(0);
    #pragma unroll
    for (int ks = 0; ks < 2; ks++){
      short8 afh[4], afl[4];
      #pragma unroll
      for (int i = 0; i < 4; i++){
        const int ra = (wm*64 + i*16 + l15)*64 + ((ks*32 + kg*8) ^ sx);
        afh[i] = *(const short8*)&Ash[ra];
        afl[i] = *(const short8*)&Asl[ra];
      }
      #pragma unroll
      for (int i = 0; i < 4; i++)
        #pragma unroll
        for (int j = 0; j < 4; j++){
          acc[i][j] = mfma_bf16(afh[i], bvh[ks][j], acc[i][j]);
          acc[i][j] = mfma_bf16(afh[i], bvl[ks][j], acc[i][j]);
          acc[i][j] = mfma_bf16(afl[i], bvh[ks][j], acc[i][j]);
        }
    }
  }

  // fused xpos epilogue. col pairs (2ip, 2ip+1) sit in lanes (l, l^1).
  const int smask = QG ? 63 : 4095;
  #pragma unroll
  for (int j = 0; j < 4; j++){
    const long n  = bn + wn*64 + j*16 + l15;
    const int  ip = (int)(n >> 1);
    const float lsv  = __logf((2.0f*ip + 409.6f) * (1.0f/1433.6f));
    const float invf = __expf(-(float)ip * (9.2103403720f/512.0f));  // 10000^(-ip/512)
    const float sgn  = (n & 1) ? 1.0f : -1.0f;
    #pragma unroll
    for (int i = 0; i < 4; i++){
      const long mb = bm + wm*64 + i*16 + kg*4;
      #pragma unroll
      for (int r = 0; r < 4; r++){
        float x = acc[i][j][r];
        float p = __shfl_xor(x, 1);
        const float fs = (float)((int)((mb + r) & smask));
        const float scale = __expf(lsv * fs * (1.0f/512.0f));
        float sn, cs;
        __sincosf(fs * invf, &sn, &cs);
        sn *= scale; cs *= scale;
        C[(size_t)(mb + r) * N + n] = x*cs + sgn*(p*sn);
      }
    }
  }
}

// ---------------------------------------------------------------------------
// Split-precision projection: P[b*2][e][d'] += sum_s wxw[e,s]*X[b][s,d'].
// ---------------------------------------------------------------------------
__global__ __launch_bounds__(256, 2)
void proj_split(const float* __restrict__ X0, const unsigned short* __restrict__ wxh,
                const unsigned short* __restrict__ wxl, float* __restrict__ P)
{
  __shared__ __align__(16) short Wsh[64*32];
  __shared__ __align__(16) short Wsl[64*32];
  __shared__ __align__(16) short Xth[64*40];
  __shared__ __align__(16) short Xtl[64*40];
  const int t = threadIdx.x, w = t >> 6, lane = t & 63;
  const int l15 = lane & 15, kg = lane >> 4;
  const int d0 = blockIdx.x * 64;
  const int b  = blockIdx.y;
  const float* X = X0 + (size_t)b * 4096 * 1024;
  const int s0 = blockIdx.z * 512;
  const int ssr = t >> 3, ddr = (t & 7) * 8;
  floatx4 acc[4] = {};

  for (int kk = 0; kk < 512; kk += 32){
    const int s = s0 + kk;
    floatx4 x0 = *(const floatx4*)&X[(size_t)(s + ssr) * 1024 + d0 + ddr];
    floatx4 x1 = *(const floatx4*)&X[(size_t)(s + ssr) * 1024 + d0 + ddr + 4];
    __syncthreads();
    lds_dma16(&wxh[(size_t)(t >> 2) * 4096 + s + (t & 3) * 8], &Wsh[t*8]);
    lds_dma16(&wxl[(size_t)(t >> 2) * 4096 + s + (t & 3) * 8], &Wsl[t*8]);
    float xv[8] = {x0[0],x0[1],x0[2],x0[3],x1[0],x1[1],x1[2],x1[3]};
    #pragma unroll
    for (int j = 0; j < 8; j++){
      unsigned short hb = f2b(xv[j]);
      Xth[(ddr + j) * 40 + ssr] = (short)hb;
      Xtl[(ddr + j) * 40 + ssr] = (short)f2b(xv[j] - b2f(hb));
    }
    __syncthreads();
    short8 afh = *(const short8*)&Wsh[(w*16 + l15)*32 + kg*8];
    short8 afl = *(const short8*)&Wsl[(w*16 + l15)*32 + kg*8];
    #pragma unroll
    for (int j = 0; j < 4; j++){
      short8 bvh = *(const short8*)&Xth[(j*16 + l15)*40 + kg*8];
      short8 bvl = *(const short8*)&Xtl[(j*16 + l15)*40 + kg*8];
      acc[j] = mfma_bf16(afh, bvh, acc[j]);
      acc[j] = mfma_bf16(afh, bvl, acc[j]);
      acc[j] = mfma_bf16(afl, bvh, acc[j]);
    }
  }
  float* Pb = P + (size_t)(b*2) * 65536;
  #pragma unroll
  for (int j = 0; j < 4; j++)
    #pragma unroll
    for (int r = 0; r < 4; r++)
      atomicAdd(&Pb[(w*16 + kg*4 + r) * 1024 + d0 + j*16 + l15], acc[j][r]);
}

// ---------------------------------------------------------------------------
// bf16 projection for V: P[b*2+1][e][d'] += sum_s wxw_h[e,s]*X[b][s,d']
// ---------------------------------------------------------------------------
__global__ __launch_bounds__(256, 2)
void proj_bf16(const unsigned short* __restrict__ X0, const unsigned short* __restrict__ wxw_bf,
               float* __restrict__ P)
{
  __shared__ __align__(16) short Ws[64*32];
  __shared__ __align__(16) short Xt[64*40];
  const int t = threadIdx.x, w = t >> 6, lane = t & 63;
  const int l15 = lane & 15, kg = lane >> 4;
  const int d0 = blockIdx.x * 64;
  const int b  = blockIdx.y;
  const unsigned short* X = X0 + (size_t)b * 4096 * 1024;
  const int s0 = blockIdx.z * 512;
  const int ssr = t >> 3, ddr = (t & 7) * 8;
  floatx4 acc[4] = {};

  for (int kk = 0; kk < 512; kk += 32){
    const int s = s0 + kk;
    short8 xv = *(const short8*)&X[(size_t)(s + ssr) * 1024 + d0 + ddr];
    __syncthreads();
    lds_dma16(&wxw_bf[(size_t)(t >> 2) * 4096 + s + (t & 3) * 8], &Ws[t*8]);
    #pragma unroll
    for (int j = 0; j < 8; j++) Xt[(ddr + j) * 40 + ssr] = xv[j];
    __syncthreads();
    short8 af = *(const short8*)&Ws[(w*16 + l15)*32 + kg*8];
    #pragma unroll
    for (int j = 0; j < 4; j++){
      short8 bv = *(const short8*)&Xt[(j*16 + l15)*40 + kg*8];
      acc[j] = mfma_bf16(af, bv, acc[j]);
    }
  }
  float* Pb = P + (size_t)(b*2 + 1) * 65536;
  #pragma unroll
  for (int j = 0; j < 4; j++)
    #pragma unroll
    for (int r = 0; r < 4; r++)
      atomicAdd(&Pb[(w*16 + kg*4 + r) * 1024 + d0 + j*16 + l15], acc[j][r]);
}

// ---------------------------------------------------------------------------
// Per (b,h) attention + group norm. 256 threads: wave w owns e-quarter for
// scores and g-quarter for outputs; scores round-trip through LDS.
// Masked score entries are literal ZEROS (matches reference softmax).
// ---------------------------------------------------------------------------
__global__ __launch_bounds__(256)
void attn_kernel(const float* __restrict__ P, const float* __restrict__ Qx,
                 const float* __restrict__ wxb,
                 const float* __restrict__ gnw, const float* __restrict__ gnb,
                 float* __restrict__ zs, float* __restrict__ zc)
{
  __shared__ __align__(16) float kps[64*64];   // [e][d]
  __shared__ __align__(16) float vps[64*64];   // [e][f]
  __shared__ __align__(16) float scs[64*65];   // [e][s], stride 65
  __shared__ float pm[256];
  __shared__ float ym[64];
  const int t = threadIdx.x;
  const int w = t >> 6, s = t & 63;
  const int b = blockIdx.x >> 4, h = blockIdx.x & 15;
  const float* Pk = P + (size_t)(2*b) * 65536 + h*64;
  const float* Pv = Pk + 65536;

  {
    const int e = t >> 2, c = (t & 3) * 16;
    const float wb = wxb[e];
    #pragma unroll
    for (int j = 0; j < 4; j++){
      floatx4 kv = *(const floatx4*)&Pk[(size_t)e*1024 + c + 4*j];
      floatx4 vv = *(const floatx4*)&Pv[(size_t)e*1024 + c + 4*j];
      kv.x += wb; kv.y += wb; kv.z += wb; kv.w += wb;
      vv.x += wb; vv.y += wb; vv.z += wb; vv.w += wb;
      *(floatx4*)&kps[e*64 + c + 4*j] = kv;
      *(floatx4*)&vps[e*64 + c + 4*j] = vv;
    }
  }
  __syncthreads();

  float qf[64];
  const floatx4* q4 = (const floatx4*)(Qx + (size_t)(b*64 + s)*1024 + h*64);
  #pragma unroll
  for (int i = 0; i < 16; i++){
    floatx4 qq = q4[i];
    qf[4*i] = qq.x; qf[4*i+1] = qq.y; qf[4*i+2] = qq.z; qf[4*i+3] = qq.w;
  }

  #pragma unroll
  for (int eo = 0; eo < 16; eo++){
    const int e = w*16 + eo;
    const floatx4* kp4 = (const floatx4*)&kps[e*64];
    float dot = 0.f;
    #pragma unroll
    for (int d = 0; d < 16; d++){
      floatx4 kv = kp4[d];
      dot += qf[4*d]*kv.x + qf[4*d+1]*kv.y + qf[4*d+2]*kv.z + qf[4*d+3]*kv.w;
    }
    scs[e*65 + s] = dot;
  }
  {
    float am = 0.f;
    #pragma unroll
    for (int eo = 0; eo < 16; eo++) am += vps[(w*16 + eo)*64 + s];
    pm[t] = am;
  }
  __syncthreads();

  const float lg = -3.4657359028f - 0.1848392483f * (float)h;
  const float gamma = 1.0f - __expf(lg);
  float sc[64];
  #pragma unroll
  for (int e = 0; e < 64; e++) sc[e] = scs[e*65 + s];
  float dec = 1.0f;
  #pragma unroll
  for (int e = 0; e < 64; e++){
    bool on = (e >= s);
    sc[e] = on ? sc[e]*dec : 0.0f;
    if (on) dec *= gamma;
  }
  float mx = -1e30f;
  #pragma unroll
  for (int e = 0; e < 64; e++) mx = fmaxf(mx, sc[e]);
  float Z = 0.f;
  #pragma unroll
  for (int e = 0; e < 64; e++){ sc[e] = __expf(sc[e] - mx); Z += sc[e]; }
  const float rz = 1.0f / Z;

  #pragma unroll
  for (int go = 0; go < 4; go++){
    const int g = w*4 + go;
    floatx4 y = {0.f,0.f,0.f,0.f};
    #pragma unroll
    for (int e = 0; e < 64; e++){
      floatx4 vv = *(const floatx4*)&vps[e*64 + g*4];
      y += sc[e] * vv;
    }
    y *= rz;
    float mu = (y.x + y.y + y.z + y.w) * 0.25f;
    float a0 = y.x-mu, a1 = y.y-mu, a2 = y.z-mu, a3 = y.w-mu;
    float inv = rsqrtf((a0*a0 + a1*a1 + a2*a2 + a3*a3)*0.25f + 1e-5f);
    floatx4 o;
    o.x = a0*inv*gnw[g*4+0] + gnb[g*4+0];
    o.y = a1*inv*gnw[g*4+1] + gnb[g*4+1];
    o.z = a2*inv*gnw[g*4+2] + gnb[g*4+2];
    o.w = a3*inv*gnw[g*4+3] + gnb[g*4+3];
    *(floatx4*)&zs[(size_t)(b*64 + s)*1024 + h*64 + g*4] = o;
  }

  if (w == 0)
    ym[s] = (pm[s] + pm[64+s] + pm[128+s] + pm[192+s]) * (1.0f/64.0f);
  __syncthreads();
  if (t < 16){
    float a0 = ym[t*4], a1 = ym[t*4+1], a2 = ym[t*4+2], a3 = ym[t*4+3];
    float mu = (a0+a1+a2+a3)*0.25f;
    a0 -= mu; a1 -= mu; a2 -= mu; a3 -= mu;
    float inv = rsqrtf((a0*a0+a1*a1+a2*a2+a3*a3)*0.25f + 1e-5f);
    zc[(size_t)b*1024 + h*64 + t*4+0] = a0*inv*gnw[t*4+0] + gnb[t*4+0];
    zc[(size_t)b*1024 + h*64 + t*4+1] = a1*inv*gnw[t*4+1] + gnb[t*4+1];
    zc[(size_t)b*1024 + h*64 + t*4+2] = a2*inv*gnw[t*4+2] + gnb[t*4+2];
    zc[(size_t)b*1024 + h*64 + t*4+3] = a3*inv*gnw[t*4+3] + gnb[t*4+3];
  }
}

// ---------------------------------------------------------------------------
// C(f32) = A(bf16) @ B(bf16)^T — final GEMM. BK=64, both DMA, swizzled LDS,
// XCD remap, pipelined stage-after-read, 3 blocks/CU.
// ---------------------------------------------------------------------------
__global__ __launch_bounds__(256, 3)
void gemm_bt(const unsigned short* __restrict__ A, const unsigned short* __restrict__ Bw,
             float* __restrict__ C, int M, int N, int K)
{
  __shared__ __align__(16) short As[128*64];
  __shared__ __align__(16) short Bs[128*64];
  const int t    = threadIdx.x;
  const int lane = t & 63;
  const int w    = t >> 6, wm = w >> 1, wn = w & 1;
  const int l15  = lane & 15, kg = lane >> 4;
  const int sx   = (l15 & 7) * 8;
  long bmi, bni; tile_remap(bmi, bni);
  const long bm = bmi * 128, bn = bni * 128;

  const int sr = t >> 3, sc8 = (t & 7) * 8;
  const int scx = sc8 ^ ((sr & 7) * 8);
  const unsigned short *pa[4], *pb[4];
  short *la[4], *lb[4];
  #pragma unroll
  for (int u = 0; u < 4; u++){
    pa[u] = A  + (bm + sr + u*32) * (size_t)K + scx;
    pb[u] = Bw + (bn + sr + u*32) * (size_t)K + scx;
    la[u] = &As[(sr + u*32)*64 + sc8];
    lb[u] = &Bs[(sr + u*32)*64 + sc8];
  }

  floatx4 acc[4][4] = {};

  #pragma unroll
  for (int u = 0; u < 4; u++){              // stage tile 0
    lds_dma16(pa[u], la[u]);
    lds_dma16(pb[u], lb[u]);
  }

  const int NT = K >> 6;
  for (int kt = 0; kt < NT; ++kt){
    __syncthreads();                        // bar1: stage(kt) landed
    short8 af[2][4], bv[2][4];              // read ALL frags before bar2
    #pragma unroll
    for (int ks = 0; ks < 2; ks++)
      #pragma unroll
      for (int i = 0; i < 4; i++){
        af[ks][i] = *(const short8*)&As[(wm*64 + i*16 + l15)*64 + ((ks*32 + kg*8) ^ sx)];
        bv[ks][i] = *(const short8*)&Bs[(wn*64 + i*16 + l15)*64 + ((ks*32 + kg*8) ^ sx)];
      }
    __syncthreads();                        // bar2: buffers free
    if (kt + 1 < NT){
      const int kn = (kt + 1) << 6;
      #pragma unroll
      for (int u = 0; u < 4; u++){
        lds_dma16(pa[u] + kn, la[u]);
        lds_dma16(pb[u] + kn, lb[u]);
      }
    }
    __builtin_amdgcn_sched_barrier(0);
    #pragma unroll
    for (int ks = 0; ks < 2; ks++)
      #pragma unroll
      for (int i = 0; i < 4; i++)
        #pragma unroll
        for (int j = 0; j < 4; j++)
          acc[i][j] = mfma_bf16(af[ks][i], bv[ks][j], acc[i][j]);
  }

  #pragma unroll
  for (int i = 0; i < 4; i++){
    const long mb = bm + wm*64 + i*16 + kg*4;
    #pragma unroll
    for (int j = 0; j < 4; j++){
      const long n = bn + wn*64 + j*16 + l15;
      #pragma unroll
      for (int r = 0; r < 4; r++)
        C[(size_t)(mb + r) * N + n] = acc[i][j][r];
    }
  }
}

// ---------------------------------------------------------------------------
extern "C" void kernel_launch(void* const* d_in, const int* in_sizes, int n_in,
                              void* d_out, int out_size, void* d_ws, size_t ws_size,
                              hipStream_t stream)
{
  const float* q   = (const float*)d_in[0];
  const float* k   = (const float*)d_in[1];
  const float* v   = (const float*)d_in[2];
  const float* wq  = (const float*)d_in[3];
  const float* wk  = (const float*)d_in[4];
  const float* wv  = (const float*)d_in[5];
  const float* wo  = (const float*)d_in[6];
  const float* wg  = (const float*)d_in[7];
  const float* wxw = (const float*)d_in[8];
  const float* wxb = (const float*)d_in[9];
  const float* gnw = (const float*)d_in[10];
  const float* gnb = (const float*)d_in[11];

  // ws layout (47.2 MB). d_out (f32, 64 MB) doubles as Kx f32 scratch.
  char* ws = (char*)d_ws;
  unsigned short* A0   = (unsigned short*)(ws);             // 32 MB: Vx bf16 -> Agate bf16
  unsigned short* wh   = (unsigned short*)(ws + 33554432);  // 2 MB: wk_h -> wq_h
  unsigned short* wl   = (unsigned short*)(ws + 35651584);  // 2 MB: wk_l -> wq_l
  unsigned short* wAbf = (unsigned short*)(ws + 37748736);  // 2 MB: wv -> wo
  unsigned short* wgbf = (unsigned short*)(ws + 39845888);  // 2 MB
  unsigned short* wxh  = (unsigned short*)(ws + 41943040);  // 512 KB
  unsigned short* wxl  = (unsigned short*)(ws + 42467328);  // 512 KB
  float*          P    = (float*)(ws + 42991616);           // 2 MB
  float*          zs   = (float*)(ws + 45088768);           // 1 MB
  float*          zc   = (float*)(ws + 46137344);           // 16 KB
  float*          Qx   = (float*)(ws + 46153728);           // 1 MB
  float*          Kx   = (float*)d_out;                     // 64 MB f32 scratch

  const int M = 16384, N = 1024, K = 1024;
  dim3 blk(256);

  // weight prep
  cvt_split<<<512, blk, 0, stream>>>(wk, wh, wl, 131072);
  cvt_split<<<128, blk, 0, stream>>>(wxw, wxh, wxl, 32768);
  cvt_kernel<<<512, blk, 0, stream>>>(wv, wAbf, 131072);
  cvt_kernel<<<512, blk, 0, stream>>>(wg, wgbf, 131072);
  hipMemsetAsync(P, 0, 2097152, stream);

  // K path: k @ wk^T -> Kx f32 (xpos fused in epilogue), then proj
  gemm_split<0><<<dim3(8,128), blk, 0, stream>>>(k, wh, wl, Kx, M, N, K);
  proj_split<<<dim3(16,4,8), blk, 0, stream>>>(Kx, wxh, wxl, P);

  // V path: v @ wv^T -> A0 bf16, proj
  gemm_af32<0><<<dim3(8,128), blk, 0, stream>>>(v, wAbf, A0, M, N, K, nullptr, nullptr);
  proj_bf16<<<dim3(16,4,8), blk, 0, stream>>>(A0, wxh, P);
  cvt_kernel<<<512, blk, 0, stream>>>(wo, wAbf, 131072);   // wv dead -> wo

  // Q path: gather 64 rows/batch, xpos fused, attention
  cvt_split<<<512, blk, 0, stream>>>(wq, wh, wl, 131072);  // wk dead -> wq
  gemm_split<1><<<dim3(8,2), blk, 0, stream>>>(q, wh, wl, Qx, 256, N, K);
  attn_kernel<<<64, 256, 0, stream>>>(P, Qx, wxb, gnw, gnb, zs, zc);

  // Gate path: G = silu((q @ wg^T) * z) fused in epilogue -> A0, final GEMM
  gemm_af32<1><<<dim3(8,128), blk, 0, stream>>>(q, wgbf, A0, M, N, K, zs, zc);
  gemm_bt<<<dim3(8,128), blk, 0, stream>>>(A0, wAbf, (float*)d_out, M, N, K);
}

// Round 8
// 565.176 us; speedup vs baseline: 1.1223x; 1.0547x over previous
//
#include <hip/hip_runtime.h>
#include <hip/hip_bf16.h>

#define DEVI __device__ __forceinline__

typedef __attribute__((ext_vector_type(8))) short  short8;
typedef __attribute__((ext_vector_type(4))) float  floatx4;
typedef __attribute__((ext_vector_type(8))) __bf16 bf16x8;

DEVI float b2f(unsigned short u){ union{unsigned int i; float f;} x; x.i=((unsigned int)u)<<16; return x.f; }
DEVI unsigned short f2b(float f){
  union{float ff; unsigned int i;} x; x.ff=f;
  unsigned int r = x.i + 0x7fffu + ((x.i>>16)&1u);
  return (unsigned short)(r>>16);
}

DEVI void lds_dma16(const void* g, void* l){
  __builtin_amdgcn_global_load_lds((const __attribute__((address_space(1))) void*)g,
                                   (__attribute__((address_space(3))) void*)l, 16, 0, 0);
}

DEVI floatx4 mfma_bf16(short8 a, short8 b, floatx4 c){
  return __builtin_amdgcn_mfma_f32_16x16x32_bf16(
      __builtin_bit_cast(bf16x8, a), __builtin_bit_cast(bf16x8, b), c, 0, 0, 0);
}

// XCD-chunked tile remap (T1), generalized. For grids with gridDim.y%8==0:
// xcd = flat&7 owns (gridDim.y/8) contiguous bm values x all bn.
// Verified identical to the R4-measured mapping for dim3(8,128)
// (FETCH 266MB -> 65.6MB); hand-checked bijective for (8,64) and (4,128).
// Identity otherwise (e.g. the (8,2) Q gemm).
DEVI void tile_remap(long& bmi, long& bni){
  const int bx = blockIdx.x, by = blockIdx.y;
  if ((gridDim.y & 7) == 0 && gridDim.y >= 8){
    const int flat = bx + gridDim.x * by;
    const int xcd  = flat & 7;
    const int idx  = flat >> 3;
    bni = (long)(idx % gridDim.x);
    bmi = (long)(xcd * (gridDim.y >> 3) + idx / gridDim.x);
  } else {
    bni = bx; bmi = by;
  }
}

// LDS swizzle (both-sides XOR, rule 21), verified 0 bank conflicts R3-R7:
// LDS(row, c) holds global chunk c ^ (row&7); DMA dest linear (base+lane*16),
// SOURCE column inverse-permuted; fragment reads XOR with (l15&7)*8.

// ---------------------------------------------------------------------------
// f32 -> bf16 (single) elementwise
// ---------------------------------------------------------------------------
__global__ void cvt_kernel(const float* __restrict__ src, unsigned short* __restrict__ dst, int n8)
{
  const int i = blockIdx.x * 256 + threadIdx.x;
  if (i >= n8) return;
  floatx4 a = ((const floatx4*)src)[2*(size_t)i];
  floatx4 b = ((const floatx4*)src)[2*(size_t)i + 1];
  short8 o;
  o[0]=(short)f2b(a[0]); o[1]=(short)f2b(a[1]); o[2]=(short)f2b(a[2]); o[3]=(short)f2b(a[3]);
  o[4]=(short)f2b(b[0]); o[5]=(short)f2b(b[1]); o[6]=(short)f2b(b[2]); o[7]=(short)f2b(b[3]);
  *(short8*)&dst[(size_t)i*8] = o;
}

// ---------------------------------------------------------------------------
// f32 -> (hi, lo) bf16 split: hi = rne(x), lo = rne(x - hi).
// ---------------------------------------------------------------------------
__global__ void cvt_split(const float* __restrict__ src, unsigned short* __restrict__ dh,
                          unsigned short* __restrict__ dl, int n8)
{
  const int i = blockIdx.x * 256 + threadIdx.x;
  if (i >= n8) return;
  floatx4 a = ((const floatx4*)src)[2*(size_t)i];
  floatx4 b = ((const floatx4*)src)[2*(size_t)i + 1];
  short8 h, l;
  #pragma unroll
  for (int j = 0; j < 8; j++){
    float x = (j < 4) ? a[j] : b[j-4];
    unsigned short hb = f2b(x);
    h[j] = (short)hb;
    l[j] = (short)f2b(x - b2f(hb));
  }
  *(short8*)&dh[(size_t)i*8] = h;
  *(short8*)&dl[(size_t)i*8] = l;
}

// ---------------------------------------------------------------------------
// C(f32) = xpos( Ahl @ Bhl^T ) 3-term, ALL FOUR streams pre-split bf16 and
// DMA-staged (zero in-loop VALU cvt). 128x128, BK=64, swizzled LDS, XCD remap.
// Row offset of C must be a multiple of 4096 so position = local row & 4095.
// ---------------------------------------------------------------------------
__global__ __launch_bounds__(256, 2)
void gemm_split3(const unsigned short* __restrict__ Ah, const unsigned short* __restrict__ Al,
                 const unsigned short* __restrict__ Bh, const unsigned short* __restrict__ Bl,
                 float* __restrict__ C, int M, int N, int K)
{
  __shared__ __align__(16) short Ash[128*64];
  __shared__ __align__(16) short Asl[128*64];
  __shared__ __align__(16) short Bsh[128*64];
  __shared__ __align__(16) short Bsl[128*64];
  const int t = threadIdx.x, lane = t & 63;
  const int w = t >> 6, wm = w >> 1, wn = w & 1;
  const int l15 = lane & 15, kg = lane >> 4;
  const int sx = (l15 & 7) * 8;
  long bmi, bni; tile_remap(bmi, bni);
  const long bm = bmi * 128, bn = bni * 128;

  size_t aoff[4], boff[4]; int ldst[4];
  #pragma unroll
  for (int u = 0; u < 4; u++){
    const int cl = u*256 + t, row = cl >> 3, cr = cl & 7;
    const int csrc = (cr ^ (row & 7)) * 8;
    aoff[u] = (size_t)(bm + row) * K + csrc;
    boff[u] = (size_t)(bn + row) * K + csrc;
    ldst[u] = cl * 8;
  }

  floatx4 acc[4][4] = {};
  #pragma unroll
  for (int u = 0; u < 4; u++){
    lds_dma16(Ah + aoff[u], &Ash[ldst[u]]);
    lds_dma16(Al + aoff[u], &Asl[ldst[u]]);
    lds_dma16(Bh + boff[u], &Bsh[ldst[u]]);
    lds_dma16(Bl + boff[u], &Bsl[ldst[u]]);
  }

  const int NT = K >> 6;
  for (int kt = 0; kt < NT; ++kt){
    __syncthreads();                         // stage(kt) landed
    short8 afh[2][4], afl[2][4], bvh[2][4], bvl[2][4];
    #pragma unroll
    for (int ks = 0; ks < 2; ks++)
      #pragma unroll
      for (int i = 0; i < 4; i++){
        const int ra = (wm*64 + i*16 + l15)*64 + ((ks*32 + kg*8) ^ sx);
        const int rb = (wn*64 + i*16 + l15)*64 + ((ks*32 + kg*8) ^ sx);
        afh[ks][i] = *(const short8*)&Ash[ra];
        afl[ks][i] = *(const short8*)&Asl[ra];
        bvh[ks][i] = *(const short8*)&Bsh[rb];
        bvl[ks][i] = *(const short8*)&Bsl[rb];
      }
    __syncthreads();                         // all reads done; buffers free
    if (kt + 1 < NT){
      const int kn = (kt + 1) << 6;
      #pragma unroll
      for (int u = 0; u < 4; u++){
        lds_dma16(Ah + aoff[u] + kn, &Ash[ldst[u]]);
        lds_dma16(Al + aoff[u] + kn, &Asl[ldst[u]]);
        lds_dma16(Bh + boff[u] + kn, &Bsh[ldst[u]]);
        lds_dma16(Bl + boff[u] + kn, &Bsl[ldst[u]]);
      }
    }
    __builtin_amdgcn_sched_barrier(0);
    #pragma unroll
    for (int ks = 0; ks < 2; ks++)
      #pragma unroll
      for (int i = 0; i < 4; i++)
        #pragma unroll
        for (int j = 0; j < 4; j++){
          acc[i][j] = mfma_bf16(afh[ks][i], bvh[ks][j], acc[i][j]);
          acc[i][j] = mfma_bf16(afh[ks][i], bvl[ks][j], acc[i][j]);
          acc[i][j] = mfma_bf16(afl[ks][i], bvh[ks][j], acc[i][j]);
        }
  }

  // fused xpos epilogue. col pairs (2ip, 2ip+1) sit in lanes (l, l^1).
  #pragma unroll
  for (int j = 0; j < 4; j++){
    const long n  = bn + wn*64 + j*16 + l15;
    const int  ip = (int)(n >> 1);
    const float lsv  = __logf((2.0f*ip + 409.6f) * (1.0f/1433.6f));
    const float invf = __expf(-(float)ip * (9.2103403720f/512.0f));  // 10000^(-ip/512)
    const float sgn  = (n & 1) ? 1.0f : -1.0f;
    #pragma unroll
    for (int i = 0; i < 4; i++){
      const long mb = bm + wm*64 + i*16 + kg*4;
      #pragma unroll
      for (int r = 0; r < 4; r++){
        float x = acc[i][j][r];
        float p = __shfl_xor(x, 1);
        const float fs = (float)((int)((mb + r) & 4095));
        const float scale = __expf(lsv * fs * (1.0f/512.0f));
        float sn, cs;
        __sincosf(fs * invf, &sn, &cs);
        sn *= scale; cs *= scale;
        C[(size_t)(mb + r) * N + n] = x*cs + sgn*(p*sn);
      }
    }
  }
}

// ---------------------------------------------------------------------------
// C(bf16) = A(f32) @ Bw(bf16)^T.  BM=128 x BN=256, BK=64. B double-buffered
// (DMA), A reg-staged. acc 4x8 per wave -> 2x MFMA per barrier drain.
// GATE=1: fused z*silu epilogue.
// ---------------------------------------------------------------------------
template<int GATE>
__global__ __launch_bounds__(256, 2)
void gemm_af32(const float* __restrict__ A, const unsigned short* __restrict__ Bw,
               unsigned short* __restrict__ C, int M, int N, int K,
               const float* __restrict__ zs, const float* __restrict__ zc)
{
  __shared__ __align__(16) short As[128*64];        // 16 KB
  __shared__ __align__(16) short Bs[2][256*64];     // 2 x 32 KB
  const int t = threadIdx.x, lane = t & 63;
  const int w = t >> 6, wm = w >> 1, wn = w & 1;
  const int l15 = lane & 15, kg = lane >> 4;
  const int sx = (l15 & 7) * 8;
  long bmi, bni; tile_remap(bmi, bni);
  const long bm = bmi * 128, bn = bni * 256;

  size_t boff[8]; int bdst[8];
  #pragma unroll
  for (int u = 0; u < 8; u++){
    const int cl = u*256 + t, row = cl >> 3, cr = cl & 7;
    boff[u] = (size_t)(bn + row) * K + (cr ^ (row & 7)) * 8;
    bdst[u] = cl * 8;
  }
  const int sr = t >> 3, sc8 = (t & 7) * 8;
  const int scx = sc8 ^ ((sr & 7) * 8);
  const float* pa[4]; short* la[4];
  #pragma unroll
  for (int u = 0; u < 4; u++){
    pa[u] = A + (bm + sr + u*32) * (size_t)K + sc8;
    la[u] = &As[(sr + u*32)*64 + scx];
  }

  floatx4 acc[4][8] = {};
  floatx4 cur[8];
  #pragma unroll
  for (int u = 0; u < 4; u++){
    cur[2*u]   = *(const floatx4*)(pa[u]);
    cur[2*u+1] = *(const floatx4*)(pa[u] + 4);
  }
  #pragma unroll
  for (int u = 0; u < 8; u++) lds_dma16(Bw + boff[u], &Bs[0][bdst[u]]);

  const int NT = K >> 6;
  int o = 0;
  for (int kt = 0; kt < NT; ++kt){
    __syncthreads();                       // B(kt)->Bs[o] landed; As reads done
    #pragma unroll
    for (int u = 0; u < 4; u++){           // ds_write A(kt) from cur
      short8 h;
      #pragma unroll
      for (int j = 0; j < 8; j++){
        float x = (j < 4) ? cur[2*u][j] : cur[2*u+1][j-4];
        h[j] = (short)f2b(x);
      }
      *(short8*)la[u] = h;
    }
    __syncthreads();                       // As visible; Bs[o^1] free
    const int kn = (kt + 1 < NT) ? ((kt + 1) << 6) : 0;
    if (kt + 1 < NT){
      #pragma unroll
      for (int u = 0; u < 8; u++) lds_dma16(Bw + boff[u] + kn, &Bs[o^1][bdst[u]]);
    }
    #pragma unroll
    for (int u = 0; u < 4; u++){           // cur <- A(kt+1), flies under MFMA
      cur[2*u]   = *(const floatx4*)(pa[u] + kn);
      cur[2*u+1] = *(const floatx4*)(pa[u] + kn + 4);
    }
    __builtin_amdgcn_sched_barrier(0);
    #pragma unroll
    for (int ks = 0; ks < 2; ks++){
      short8 af[4], bv[8];
      #pragma unroll
      for (int i = 0; i < 4; i++)
        af[i] = *(const short8*)&As[(wm*64 + i*16 + l15)*64 + ((ks*32 + kg*8) ^ sx)];
      #pragma unroll
      for (int j = 0; j < 8; j++)
        bv[j] = *(const short8*)&Bs[o][(wn*128 + j*16 + l15)*64 + ((ks*32 + kg*8) ^ sx)];
      #pragma unroll
      for (int i = 0; i < 4; i++)
        #pragma unroll
        for (int j = 0; j < 8; j++)
          acc[i][j] = mfma_bf16(af[i], bv[j], acc[i][j]);
    }
    o ^= 1;
  }

  if (GATE){
    #pragma unroll
    for (int i = 0; i < 4; i++){
      const long mb = bm + wm*64 + i*16 + kg*4;
      #pragma unroll
      for (int r = 0; r < 4; r++){
        const long row = mb + r;
        const int  ss  = (int)(row & 4095);
        const long bb  = row >> 12;
        const float* zr = (ss < 64) ? (zs + (((size_t)(bb*64 + ss)) << 10))
                                    : (zc + ((size_t)bb << 10));
        #pragma unroll
        for (int j = 0; j < 8; j++){
          const long n = bn + wn*128 + j*16 + l15;
          float g = acc[i][j][r] * zr[n];
          float sig = 1.0f / (1.0f + __expf(-g));
          C[(size_t)row * N + n] = f2b(g * sig);
        }
      }
    }
  } else {
    #pragma unroll
    for (int i = 0; i < 4; i++){
      const long mb = bm + wm*64 + i*16 + kg*4;
      #pragma unroll
      for (int j = 0; j < 8; j++){
        const long n = bn + wn*128 + j*16 + l15;
        #pragma unroll
        for (int r = 0; r < 4; r++)
          C[(size_t)(mb + r) * N + n] = f2b(acc[i][j][r]);
      }
    }
  }
}

// ---------------------------------------------------------------------------
// Q-path only: C(f32) = xpos( A(f32) @ B^T ) split-bf16 reg-staged.
// Grid (8,2) -> tile_remap identity. Gather r -> (r>>6)*4096 + (r&63).
// ---------------------------------------------------------------------------
template<int QG>
__global__ __launch_bounds__(256, 2)
void gemm_split(const float* __restrict__ A, const unsigned short* __restrict__ Bh,
                const unsigned short* __restrict__ Bl, float* __restrict__ C,
                int M, int N, int K)
{
  __shared__ __align__(16) short Ash[128*64];
  __shared__ __align__(16) short Asl[128*64];
  __shared__ __align__(16) short Bsh[128*64];
  __shared__ __align__(16) short Bsl[128*64];
  const int t    = threadIdx.x;
  const int lane = t & 63;
  const int w    = t >> 6, wm = w >> 1, wn = w & 1;
  const int l15  = lane & 15, kg = lane >> 4;
  const int sx   = (l15 & 7) * 8;
  long bmi, bni; tile_remap(bmi, bni);
  const long bm = bmi * 128, bn = bni * 128;

  const int sr = t >> 3, sc8 = (t & 7) * 8;
  const int scx = sc8 ^ ((sr & 7) * 8);
  const unsigned short *pbh[4], *pbl[4];
  const float* pa[4];
  short *lbh[4], *lbl[4], *lah[4], *lal[4];
  #pragma unroll
  for (int u = 0; u < 4; u++){
    pbh[u] = Bh + (bn + sr + u*32) * (size_t)K + scx;
    pbl[u] = Bl + (bn + sr + u*32) * (size_t)K + scx;
    long ar = bm + sr + u*32;
    if (QG) ar = (ar >> 6) * 4096 + (ar & 63);
    pa[u]  = A + ar * (size_t)K + sc8;
    lbh[u] = &Bsh[(sr + u*32)*64 + sc8];
    lbl[u] = &Bsl[(sr + u*32)*64 + sc8];
    lah[u] = &Ash[(sr + u*32)*64 + scx];
    lal[u] = &Asl[(sr + u*32)*64 + scx];
  }

  floatx4 acc[4][4] = {};
  floatx4 cur[8];
  #pragma unroll
  for (int u = 0; u < 4; u++){
    cur[2*u]   = *(const floatx4*)(pa[u]);
    cur[2*u+1] = *(const floatx4*)(pa[u] + 4);
  }
  #pragma unroll
  for (int u = 0; u < 4; u++){
    lds_dma16(pbh[u], lbh[u]);
    lds_dma16(pbl[u], lbl[u]);
  }

  const int NT = K >> 6;
  for (int kt = 0; kt < NT; ++kt){
    __syncthreads();
    #pragma unroll
    for (int u = 0; u < 4; u++){
      short8 h, l;
      #pragma unroll
      for (int j = 0; j < 8; j++){
        float x = (j < 4) ? cur[2*u][j] : cur[2*u+1][j-4];
        unsigned short hb = f2b(x);
        h[j] = (short)hb;
        l[j] = (short)f2b(x - b2f(hb));
      }
      *(short8*)lah[u] = h;
      *(short8*)lal[u] = l;
    }
    short8 bvh[2][4], bvl[2][4];
    #pragma unroll
    for (int ks = 0; ks < 2; ks++)
      #pragma unroll
      for (int i = 0; i < 4; i++){
        const int rb = (wn*64 + i*16 + l15)*64 + ((ks*32 + kg*8) ^ sx);
        bvh[ks][i] = *(const short8*)&Bsh[rb];
        bvl[ks][i] = *(const short8*)&Bsl[rb];
      }
    __syncthreads();
    const int kn = (kt + 1 < NT) ? ((kt + 1) << 6) : 0;
    if (kt + 1 < NT){
      #pragma unroll
      for (int u = 0; u < 4; u++){
        lds_dma16(pbh[u] + kn, lbh[u]);
        lds_dma16(pbl[u] + kn, lbl[u]);
      }
    }
    #pragma unroll
    for (int u = 0; u < 4; u++){
      cur[2*u]   = *(const floatx4*)(pa[u] + kn);
      cur[2*u+1] = *(const floatx4*)(pa[u] + kn + 4);
    }
    __builtin_amdgcn_sched_barrier(0);
    #pragma unroll
    for (int ks = 0; ks < 2; ks++){
      short8 afh[4], afl[4];
      #pragma unroll
      for (int i = 0; i < 4; i++){
        const int ra = (wm*64 + i*16 + l15)*64 + ((ks*32 + kg*8) ^ sx);
        afh[i] = *(const short8*)&Ash[ra];
        afl[i] = *(const short8*)&Asl[ra];
      }
      #pragma unroll
      for (int i = 0; i < 4; i++)
        #pragma unroll
        for (int j = 0; j < 4; j++){
          acc[i][j] = mfma_bf16(afh[i], bvh[ks][j], acc[i][j]);
          acc[i][j] = mfma_bf16(afh[i], bvl[ks][j], acc[i][j]);
          acc[i][j] = mfma_bf16(afl[i], bvh[ks][j], acc[i][j]);
        }
    }
  }

  const int smask = QG ? 63 : 4095;
  #pragma unroll
  for (int j = 0; j < 4; j++){
    const long n  = bn + wn*64 + j*16 + l15;
    const int  ip = (int)(n >> 1);
    const float lsv  = __logf((2.0f*ip + 409.6f) * (1.0f/1433.6f));
    const float invf = __expf(-(float)ip * (9.2103403720f/512.0f));
    const float sgn  = (n & 1) ? 1.0f : -1.0f;
    #pragma unroll
    for (int i = 0; i < 4; i++){
      const long mb = bm + wm*64 + i*16 + kg*4;
      #pragma unroll
      for (int r = 0; r < 4; r++){
        float x = acc[i][j][r];
        float p = __shfl_xor(x, 1);
        const float fs = (float)((int)((mb + r) & smask));
        const float scale = __expf(lsv * fs * (1.0f/512.0f));
        float sn, cs;
        __sincosf(fs * invf, &sn, &cs);
        sn *= scale; cs *= scale;
        C[(size_t)(mb + r) * N + n] = x*cs + sgn*(p*sn);
      }
    }
  }
}

// ---------------------------------------------------------------------------
// Split-precision projection: P[b*2][e][d'] += sum_s wxw[e,s]*X[b][s,d'].
// ---------------------------------------------------------------------------
__global__ __launch_bounds__(256, 2)
void proj_split(const float* __restrict__ X0, const unsigned short* __restrict__ wxh,
                const unsigned short* __restrict__ wxl, float* __restrict__ P)
{
  __shared__ __align__(16) short Wsh[64*32];
  __shared__ __align__(16) short Wsl[64*32];
  __shared__ __align__(16) short Xth[64*40];
  __shared__ __align__(16) short Xtl[64*40];
  const int t = threadIdx.x, w = t >> 6, lane = t & 63;
  const int l15 = lane & 15, kg = lane >> 4;
  const int d0 = blockIdx.x * 64;
  const int b  = blockIdx.y;
  const float* X = X0 + (size_t)b * 4096 * 1024;
  const int s0 = blockIdx.z * 512;
  const int ssr = t >> 3, ddr = (t & 7) * 8;
  floatx4 acc[4] = {};

  for (int kk = 0; kk < 512; kk += 32){
    const int s = s0 + kk;
    floatx4 x0 = *(const floatx4*)&X[(size_t)(s + ssr) * 1024 + d0 + ddr];
    floatx4 x1 = *(const floatx4*)&X[(size_t)(s + ssr) * 1024 + d0 + ddr + 4];
    __syncthreads();
    lds_dma16(&wxh[(size_t)(t >> 2) * 4096 + s + (t & 3) * 8], &Wsh[t*8]);
    lds_dma16(&wxl[(size_t)(t >> 2) * 4096 + s + (t & 3) * 8], &Wsl[t*8]);
    float xv[8] = {x0[0],x0[1],x0[2],x0[3],x1[0],x1[1],x1[2],x1[3]};
    #pragma unroll
    for (int j = 0; j < 8; j++){
      unsigned short hb = f2b(xv[j]);
      Xth[(ddr + j) * 40 + ssr] = (short)hb;
      Xtl[(ddr + j) * 40 + ssr] = (short)f2b(xv[j] - b2f(hb));
    }
    __syncthreads();
    short8 afh = *(const short8*)&Wsh[(w*16 + l15)*32 + kg*8];
    short8 afl = *(const short8*)&Wsl[(w*16 + l15)*32 + kg*8];
    #pragma unroll
    for (int j = 0; j < 4; j++){
      short8 bvh = *(const short8*)&Xth[(j*16 + l15)*40 + kg*8];
      short8 bvl = *(const short8*)&Xtl[(j*16 + l15)*40 + kg*8];
      acc[j] = mfma_bf16(afh, bvh, acc[j]);
      acc[j] = mfma_bf16(afh, bvl, acc[j]);
      acc[j] = mfma_bf16(afl, bvh, acc[j]);
    }
  }
  float* Pb = P + (size_t)(b*2) * 65536;
  #pragma unroll
  for (int j = 0; j < 4; j++)
    #pragma unroll
    for (int r = 0; r < 4; r++)
      atomicAdd(&Pb[(w*16 + kg*4 + r) * 1024 + d0 + j*16 + l15], acc[j][r]);
}

// ---------------------------------------------------------------------------
// bf16 projection for V: P[b*2+1][e][d'] += sum_s wxw_h[e,s]*X[b][s,d']
// ---------------------------------------------------------------------------
__global__ __launch_bounds__(256, 2)
void proj_bf16(const unsigned short* __restrict__ X0, const unsigned short* __restrict__ wxw_bf,
               float* __restrict__ P)
{
  __shared__ __align__(16) short Ws[64*32];
  __shared__ __align__(16) short Xt[64*40];
  const int t = threadIdx.x, w = t >> 6, lane = t & 63;
  const int l15 = lane & 15, kg = lane >> 4;
  const int d0 = blockIdx.x * 64;
  const int b  = blockIdx.y;
  const unsigned short* X = X0 + (size_t)b * 4096 * 1024;
  const int s0 = blockIdx.z * 512;
  const int ssr = t >> 3, ddr = (t & 7) * 8;
  floatx4 acc[4] = {};

  for (int kk = 0; kk < 512; kk += 32){
    const int s = s0 + kk;
    short8 xv = *(const short8*)&X[(size_t)(s + ssr) * 1024 + d0 + ddr];
    __syncthreads();
    lds_dma16(&wxw_bf[(size_t)(t >> 2) * 4096 + s + (t & 3) * 8], &Ws[t*8]);
    #pragma unroll
    for (int j = 0; j < 8; j++) Xt[(ddr + j) * 40 + ssr] = xv[j];
    __syncthreads();
    short8 af = *(const short8*)&Ws[(w*16 + l15)*32 + kg*8];
    #pragma unroll
    for (int j = 0; j < 4; j++){
      short8 bv = *(const short8*)&Xt[(j*16 + l15)*40 + kg*8];
      acc[j] = mfma_bf16(af, bv, acc[j]);
    }
  }
  float* Pb = P + (size_t)(b*2 + 1) * 65536;
  #pragma unroll
  for (int j = 0; j < 4; j++)
    #pragma unroll
    for (int r = 0; r < 4; r++)
      atomicAdd(&Pb[(w*16 + kg*4 + r) * 1024 + d0 + j*16 + l15], acc[j][r]);
}

// ---------------------------------------------------------------------------
// Per (b,h) attention + group norm. 256 threads: wave w owns e-quarter for
// scores and g-quarter for outputs; scores round-trip through LDS.
// Masked score entries are literal ZEROS (matches reference softmax).
// ---------------------------------------------------------------------------
__global__ __launch_bounds__(256)
void attn_kernel(const float* __restrict__ P, const float* __restrict__ Qx,
                 const float* __restrict__ wxb,
                 const float* __restrict__ gnw, const float* __restrict__ gnb,
                 float* __restrict__ zs, float* __restrict__ zc)
{
  __shared__ __align__(16) float kps[64*64];   // [e][d]
  __shared__ __align__(16) float vps[64*64];   // [e][f]
  __shared__ __align__(16) float scs[64*65];   // [e][s], stride 65
  __shared__ float pm[256];
  __shared__ float ym[64];
  const int t = threadIdx.x;
  const int w = t >> 6, s = t & 63;
  const int b = blockIdx.x >> 4, h = blockIdx.x & 15;
  const float* Pk = P + (size_t)(2*b) * 65536 + h*64;
  const float* Pv = Pk + 65536;

  {
    const int e = t >> 2, c = (t & 3) * 16;
    const float wb = wxb[e];
    #pragma unroll
    for (int j = 0; j < 4; j++){
      floatx4 kv = *(const floatx4*)&Pk[(size_t)e*1024 + c + 4*j];
      floatx4 vv = *(const floatx4*)&Pv[(size_t)e*1024 + c + 4*j];
      kv.x += wb; kv.y += wb; kv.z += wb; kv.w += wb;
      vv.x += wb; vv.y += wb; vv.z += wb; vv.w += wb;
      *(floatx4*)&kps[e*64 + c + 4*j] = kv;
      *(floatx4*)&vps[e*64 + c + 4*j] = vv;
    }
  }
  __syncthreads();

  float qf[64];
  const floatx4* q4 = (const floatx4*)(Qx + (size_t)(b*64 + s)*1024 + h*64);
  #pragma unroll
  for (int i = 0; i < 16; i++){
    floatx4 qq = q4[i];
    qf[4*i] = qq.x; qf[4*i+1] = qq.y; qf[4*i+2] = qq.z; qf[4*i+3] = qq.w;
  }

  #pragma unroll
  for (int eo = 0; eo < 16; eo++){
    const int e = w*16 + eo;
    const floatx4* kp4 = (const floatx4*)&kps[e*64];
    float dot = 0.f;
    #pragma unroll
    for (int d = 0; d < 16; d++){
      floatx4 kv = kp4[d];
      dot += qf[4*d]*kv.x + qf[4*d+1]*kv.y + qf[4*d+2]*kv.z + qf[4*d+3]*kv.w;
    }
    scs[e*65 + s] = dot;
  }
  {
    float am = 0.f;
    #pragma unroll
    for (int eo = 0; eo < 16; eo++) am += vps[(w*16 + eo)*64 + s];
    pm[t] = am;
  }
  __syncthreads();

  const float lg = -3.4657359028f - 0.1848392483f * (float)h;
  const float gamma = 1.0f - __expf(lg);
  float sc[64];
  #pragma unroll
  for (int e = 0; e < 64; e++) sc[e] = scs[e*65 + s];
  float dec = 1.0f;
  #pragma unroll
  for (int e = 0; e < 64; e++){
    bool on = (e >= s);
    sc[e] = on ? sc[e]*dec : 0.0f;
    if (on) dec *= gamma;
  }
  float mx = -1e30f;
  #pragma unroll
  for (int e = 0; e < 64; e++) mx = fmaxf(mx, sc[e]);
  float Z = 0.f;
  #pragma unroll
  for (int e = 0; e < 64; e++){ sc[e] = __expf(sc[e] - mx); Z += sc[e]; }
  const float rz = 1.0f / Z;

  #pragma unroll
  for (int go = 0; go < 4; go++){
    const int g = w*4 + go;
    floatx4 y = {0.f,0.f,0.f,0.f};
    #pragma unroll
    for (int e = 0; e < 64; e++){
      floatx4 vv = *(const floatx4*)&vps[e*64 + g*4];
      y += sc[e] * vv;
    }
    y *= rz;
    float mu = (y.x + y.y + y.z + y.w) * 0.25f;
    float a0 = y.x-mu, a1 = y.y-mu, a2 = y.z-mu, a3 = y.w-mu;
    float inv = rsqrtf((a0*a0 + a1*a1 + a2*a2 + a3*a3)*0.25f + 1e-5f);
    floatx4 o;
    o.x = a0*inv*gnw[g*4+0] + gnb[g*4+0];
    o.y = a1*inv*gnw[g*4+1] + gnb[g*4+1];
    o.z = a2*inv*gnw[g*4+2] + gnb[g*4+2];
    o.w = a3*inv*gnw[g*4+3] + gnb[g*4+3];
    *(floatx4*)&zs[(size_t)(b*64 + s)*1024 + h*64 + g*4] = o;
  }

  if (w == 0)
    ym[s] = (pm[s] + pm[64+s] + pm[128+s] + pm[192+s]) * (1.0f/64.0f);
  __syncthreads();
  if (t < 16){
    float a0 = ym[t*4], a1 = ym[t*4+1], a2 = ym[t*4+2], a3 = ym[t*4+3];
    float mu = (a0+a1+a2+a3)*0.25f;
    a0 -= mu; a1 -= mu; a2 -= mu; a3 -= mu;
    float inv = rsqrtf((a0*a0+a1*a1+a2*a2+a3*a3)*0.25f + 1e-5f);
    zc[(size_t)b*1024 + h*64 + t*4+0] = a0*inv*gnw[t*4+0] + gnb[t*4+0];
    zc[(size_t)b*1024 + h*64 + t*4+1] = a1*inv*gnw[t*4+1] + gnb[t*4+1];
    zc[(size_t)b*1024 + h*64 + t*4+2] = a2*inv*gnw[t*4+2] + gnb[t*4+2];
    zc[(size_t)b*1024 + h*64 + t*4+3] = a3*inv*gnw[t*4+3] + gnb[t*4+3];
  }
}

// ---------------------------------------------------------------------------
// C(f32) = A(bf16) @ B(bf16)^T — final GEMM. BK=64, both DMA, swizzled LDS,
// XCD remap, pipelined stage-after-read, 3 blocks/CU. (unchanged this round)
// ---------------------------------------------------------------------------
__global__ __launch_bounds__(256, 3)
void gemm_bt(const unsigned short* __restrict__ A, const unsigned short* __restrict__ Bw,
             float* __restrict__ C, int M, int N, int K)
{
  __shared__ __align__(16) short As[128*64];
  __shared__ __align__(16) short Bs[128*64];
  const int t    = threadIdx.x;
  const int lane = t & 63;
  const int w    = t >> 6, wm = w >> 1, wn = w & 1;
  const int l15  = lane & 15, kg = lane >> 4;
  const int sx   = (l15 & 7) * 8;
  long bmi, bni; tile_remap(bmi, bni);
  const long bm = bmi * 128, bn = bni * 128;

  const int sr = t >> 3, sc8 = (t & 7) * 8;
  const int scx = sc8 ^ ((sr & 7) * 8);
  const unsigned short *pa[4], *pb[4];
  short *la[4], *lb[4];
  #pragma unroll
  for (int u = 0; u < 4; u++){
    pa[u] = A  + (bm + sr + u*32) * (size_t)K + scx;
    pb[u] = Bw + (bn + sr + u*32) * (size_t)K + scx;
    la[u] = &As[(sr + u*32)*64 + sc8];
    lb[u] = &Bs[(sr + u*32)*64 + sc8];
  }

  floatx4 acc[4][4] = {};

  #pragma unroll
  for (int u = 0; u < 4; u++){
    lds_dma16(pa[u], la[u]);
    lds_dma16(pb[u], lb[u]);
  }

  const int NT = K >> 6;
  for (int kt = 0; kt < NT; ++kt){
    __syncthreads();
    short8 af[2][4], bv[2][4];
    #pragma unroll
    for (int ks = 0; ks < 2; ks++)
      #pragma unroll
      for (int i = 0; i < 4; i++){
        af[ks][i] = *(const short8*)&As[(wm*64 + i*16 + l15)*64 + ((ks*32 + kg*8) ^ sx)];
        bv[ks][i] = *(const short8*)&Bs[(wn*64 + i*16 + l15)*64 + ((ks*32 + kg*8) ^ sx)];
      }
    __syncthreads();
    if (kt + 1 < NT){
      const int kn = (kt + 1) << 6;
      #pragma unroll
      for (int u = 0; u < 4; u++){
        lds_dma16(pa[u] + kn, la[u]);
        lds_dma16(pb[u] + kn, lb[u]);
      }
    }
    __builtin_amdgcn_sched_barrier(0);
    #pragma unroll
    for (int ks = 0; ks < 2; ks++)
      #pragma unroll
      for (int i = 0; i < 4; i++)
        #pragma unroll
        for (int j = 0; j < 4; j++)
          acc[i][j] = mfma_bf16(af[ks][i], bv[ks][j], acc[i][j]);
  }

  #pragma unroll
  for (int i = 0; i < 4; i++){
    const long mb = bm + wm*64 + i*16 + kg*4;
    #pragma unroll
    for (int j = 0; j < 4; j++){
      const long n = bn + wn*64 + j*16 + l15;
      #pragma unroll
      for (int r = 0; r < 4; r++)
        C[(size_t)(mb + r) * N + n] = acc[i][j][r];
    }
  }
}

// ---------------------------------------------------------------------------
extern "C" void kernel_launch(void* const* d_in, const int* in_sizes, int n_in,
                              void* d_out, int out_size, void* d_ws, size_t ws_size,
                              hipStream_t stream)
{
  const float* q   = (const float*)d_in[0];
  const float* k   = (const float*)d_in[1];
  const float* v   = (const float*)d_in[2];
  const float* wq  = (const float*)d_in[3];
  const float* wk  = (const float*)d_in[4];
  const float* wv  = (const float*)d_in[5];
  const float* wo  = (const float*)d_in[6];
  const float* wg  = (const float*)d_in[7];
  const float* wxw = (const float*)d_in[8];
  const float* wxb = (const float*)d_in[9];
  const float* gnw = (const float*)d_in[10];
  const float* gnb = (const float*)d_in[11];

  // ws layout (47.2 MB). d_out (f32, 64 MB) doubles as Kx f32 scratch.
  // A0 (32 MB) triple-duty: {kh|kl half-passes} -> Vx bf16 -> Agate bf16.
  char* ws = (char*)d_ws;
  unsigned short* A0   = (unsigned short*)(ws);             // 32 MB
  unsigned short* wh   = (unsigned short*)(ws + 33554432);  // 2 MB: wk_h -> wq_h
  unsigned short* wl   = (unsigned short*)(ws + 35651584);  // 2 MB: wk_l -> wq_l
  unsigned short* wAbf = (unsigned short*)(ws + 37748736);  // 2 MB: wv -> wo
  unsigned short* wgbf = (unsigned short*)(ws + 39845888);  // 2 MB
  unsigned short* wxh  = (unsigned short*)(ws + 41943040);  // 512 KB
  unsigned short* wxl  = (unsigned short*)(ws + 42467328);  // 512 KB
  float*          P    = (float*)(ws + 42991616);           // 2 MB
  float*          zs   = (float*)(ws + 45088768);           // 1 MB
  float*          zc   = (float*)(ws + 46137344);           // 16 KB
  float*          Qx   = (float*)(ws + 46153728);           // 1 MB
  float*          Kx   = (float*)d_out;                     // 64 MB f32 scratch

  const int M = 16384, N = 1024, K = 1024;
  dim3 blk(256);

  // weight prep
  cvt_split<<<512, blk, 0, stream>>>(wk, wh, wl, 131072);
  cvt_split<<<128, blk, 0, stream>>>(wxw, wxh, wxl, 32768);
  cvt_kernel<<<512, blk, 0, stream>>>(wv, wAbf, 131072);
  cvt_kernel<<<512, blk, 0, stream>>>(wg, wgbf, 131072);
  hipMemsetAsync(P, 0, 2097152, stream);

  // K path: pre-split k (half-M passes through A0), all-DMA 3-term GEMM
  // (xpos fused; row offset 8192 is a multiple of 4096 so position math holds)
  for (int p = 0; p < 2; p++){
    cvt_split<<<4096, blk, 0, stream>>>(k + (size_t)p*8388608, A0, A0 + 8388608, 1048576);
    gemm_split3<<<dim3(8,64), blk, 0, stream>>>(A0, A0 + 8388608, wh, wl,
                                                Kx + (size_t)p*8388608, 8192, N, K);
  }
  proj_split<<<dim3(16,4,8), blk, 0, stream>>>(Kx, wxh, wxl, P);

  // V path: v @ wv^T -> A0 bf16 (BN=256 widened), proj
  gemm_af32<0><<<dim3(4,128), blk, 0, stream>>>(v, wAbf, A0, M, N, K, nullptr, nullptr);
  proj_bf16<<<dim3(16,4,8), blk, 0, stream>>>(A0, wxh, P);
  cvt_kernel<<<512, blk, 0, stream>>>(wo, wAbf, 131072);   // wv dead -> wo

  // Q path: gather 64 rows/batch, xpos fused, attention
  cvt_split<<<512, blk, 0, stream>>>(wq, wh, wl, 131072);  // wk dead -> wq
  gemm_split<1><<<dim3(8,2), blk, 0, stream>>>(q, wh, wl, Qx, 256, N, K);
  attn_kernel<<<64, 256, 0, stream>>>(P, Qx, wxb, gnw, gnb, zs, zc);

  // Gate path: G = silu((q @ wg^T) * z) fused in epilogue -> A0, final GEMM
  gemm_af32<1><<<dim3(4,128), blk, 0, stream>>>(q, wgbf, A0, M, N, K, zs, zc);
  gemm_bt<<<dim3(8,128), blk, 0, stream>>>(A0, wAbf, (float*)d_out, M, N, K);
}

// Round 9
// 548.139 us; speedup vs baseline: 1.1572x; 1.0311x over previous
//
#include <hip/hip_runtime.h>
#include <hip/hip_bf16.h>

#define DEVI __device__ __forceinline__

typedef __attribute__((ext_vector_type(8))) short  short8;
typedef __attribute__((ext_vector_type(4))) float  floatx4;
typedef __attribute__((ext_vector_type(8))) __bf16 bf16x8;

DEVI float b2f(unsigned short u){ union{unsigned int i; float f;} x; x.i=((unsigned int)u)<<16; return x.f; }
// Native bf16 convert (RNE) -> compiler emits v_cvt_pk_bf16_f32 for pairs.
// Bit-identical to the previous manual round-to-nearest-even integer path.
DEVI unsigned short f2b(float f){
  return __builtin_bit_cast(unsigned short, (__bf16)f);
}

DEVI void lds_dma16(const void* g, void* l){
  __builtin_amdgcn_global_load_lds((const __attribute__((address_space(1))) void*)g,
                                   (__attribute__((address_space(3))) void*)l, 16, 0, 0);
}

DEVI floatx4 mfma_bf16(short8 a, short8 b, floatx4 c){
  return __builtin_amdgcn_mfma_f32_16x16x32_bf16(
      __builtin_bit_cast(bf16x8, a), __builtin_bit_cast(bf16x8, b), c, 0, 0, 0);
}

// XCD-chunked tile remap (T1), generalized. Verified R4: FETCH 266->65.6MB.
DEVI void tile_remap(long& bmi, long& bni){
  const int bx = blockIdx.x, by = blockIdx.y;
  if ((gridDim.y & 7) == 0 && gridDim.y >= 8){
    const int flat = bx + gridDim.x * by;
    const int xcd  = flat & 7;
    const int idx  = flat >> 3;
    bni = (long)(idx % gridDim.x);
    bmi = (long)(xcd * (gridDim.y >> 3) + idx / gridDim.x);
  } else {
    bni = bx; bmi = by;
  }
}

// LDS swizzle (both-sides XOR, rule 21), verified 0 bank conflicts R3-R8.

// ---------------------------------------------------------------------------
// elementwise conversion bodies
// ---------------------------------------------------------------------------
DEVI void cvt_body(const float* __restrict__ src, unsigned short* __restrict__ dst, int i, int n8)
{
  if (i >= n8) return;
  floatx4 a = ((const floatx4*)src)[2*(size_t)i];
  floatx4 b = ((const floatx4*)src)[2*(size_t)i + 1];
  short8 o;
  o[0]=(short)f2b(a[0]); o[1]=(short)f2b(a[1]); o[2]=(short)f2b(a[2]); o[3]=(short)f2b(a[3]);
  o[4]=(short)f2b(b[0]); o[5]=(short)f2b(b[1]); o[6]=(short)f2b(b[2]); o[7]=(short)f2b(b[3]);
  *(short8*)&dst[(size_t)i*8] = o;
}

DEVI void cvt_split_body(const float* __restrict__ src, unsigned short* __restrict__ dh,
                         unsigned short* __restrict__ dl, int i, int n8)
{
  if (i >= n8) return;
  floatx4 a = ((const floatx4*)src)[2*(size_t)i];
  floatx4 b = ((const floatx4*)src)[2*(size_t)i + 1];
  short8 h, l;
  #pragma unroll
  for (int j = 0; j < 8; j++){
    float x = (j < 4) ? a[j] : b[j-4];
    unsigned short hb = f2b(x);
    h[j] = (short)hb;
    l[j] = (short)f2b(x - b2f(hb));
  }
  *(short8*)&dh[(size_t)i*8] = h;
  *(short8*)&dl[(size_t)i*8] = l;
}

// f32 -> (hi,lo) bf16 split, standalone (K-path passes)
__global__ void cvt_split(const float* __restrict__ src, unsigned short* __restrict__ dh,
                          unsigned short* __restrict__ dl, int n8)
{
  cvt_split_body(src, dh, dl, blockIdx.x * 256 + threadIdx.x, n8);
}

// Fused weight prep: wk-split | wxw-split | wv-cvt | wg-cvt  (was 4 launches)
__global__ void wprep(const float* __restrict__ wk, unsigned short* __restrict__ wh,
                      unsigned short* __restrict__ wl,
                      const float* __restrict__ wxw, unsigned short* __restrict__ wxh,
                      unsigned short* __restrict__ wxl,
                      const float* __restrict__ wv, unsigned short* __restrict__ wvb,
                      const float* __restrict__ wg, unsigned short* __restrict__ wgb)
{
  const int blk = blockIdx.x, t = threadIdx.x;
  if (blk < 512)       cvt_split_body(wk,  wh,  wl,  blk*256 + t,        131072);
  else if (blk < 640)  cvt_split_body(wxw, wxh, wxl, (blk-512)*256 + t,  32768);
  else if (blk < 1152) cvt_body(wv, wvb, (blk-640)*256 + t,  131072);
  else                 cvt_body(wg, wgb, (blk-1152)*256 + t, 131072);
}

// Fused: wq-split + wo-cvt (was 2 launches)
__global__ void wprep2(const float* __restrict__ wq, unsigned short* __restrict__ wh,
                       unsigned short* __restrict__ wl,
                       const float* __restrict__ wo, unsigned short* __restrict__ wob)
{
  const int blk = blockIdx.x, t = threadIdx.x;
  if (blk < 512) cvt_split_body(wq, wh, wl, blk*256 + t, 131072);
  else           cvt_body(wo, wob, (blk-512)*256 + t, 131072);
}

// ---------------------------------------------------------------------------
// C(f32) = xpos( Ahl @ Bhl^T ) 3-term, all four streams pre-split bf16 and
// DMA-staged. 128x128, BK=64, swizzled LDS, XCD remap. ~930 TF measured (R8).
// Row offset of C must be a multiple of 4096 so position = local row & 4095.
// ---------------------------------------------------------------------------
__global__ __launch_bounds__(256, 2)
void gemm_split3(const unsigned short* __restrict__ Ah, const unsigned short* __restrict__ Al,
                 const unsigned short* __restrict__ Bh, const unsigned short* __restrict__ Bl,
                 float* __restrict__ C, int M, int N, int K)
{
  __shared__ __align__(16) short Ash[128*64];
  __shared__ __align__(16) short Asl[128*64];
  __shared__ __align__(16) short Bsh[128*64];
  __shared__ __align__(16) short Bsl[128*64];
  const int t = threadIdx.x, lane = t & 63;
  const int w = t >> 6, wm = w >> 1, wn = w & 1;
  const int l15 = lane & 15, kg = lane >> 4;
  const int sx = (l15 & 7) * 8;
  long bmi, bni; tile_remap(bmi, bni);
  const long bm = bmi * 128, bn = bni * 128;

  size_t aoff[4], boff[4]; int ldst[4];
  #pragma unroll
  for (int u = 0; u < 4; u++){
    const int cl = u*256 + t, row = cl >> 3, cr = cl & 7;
    const int csrc = (cr ^ (row & 7)) * 8;
    aoff[u] = (size_t)(bm + row) * K + csrc;
    boff[u] = (size_t)(bn + row) * K + csrc;
    ldst[u] = cl * 8;
  }

  floatx4 acc[4][4] = {};
  #pragma unroll
  for (int u = 0; u < 4; u++){
    lds_dma16(Ah + aoff[u], &Ash[ldst[u]]);
    lds_dma16(Al + aoff[u], &Asl[ldst[u]]);
    lds_dma16(Bh + boff[u], &Bsh[ldst[u]]);
    lds_dma16(Bl + boff[u], &Bsl[ldst[u]]);
  }

  const int NT = K >> 6;
  for (int kt = 0; kt < NT; ++kt){
    __syncthreads();                         // stage(kt) landed
    short8 afh[2][4], afl[2][4], bvh[2][4], bvl[2][4];
    #pragma unroll
    for (int ks = 0; ks < 2; ks++)
      #pragma unroll
      for (int i = 0; i < 4; i++){
        const int ra = (wm*64 + i*16 + l15)*64 + ((ks*32 + kg*8) ^ sx);
        const int rb = (wn*64 + i*16 + l15)*64 + ((ks*32 + kg*8) ^ sx);
        afh[ks][i] = *(const short8*)&Ash[ra];
        afl[ks][i] = *(const short8*)&Asl[ra];
        bvh[ks][i] = *(const short8*)&Bsh[rb];
        bvl[ks][i] = *(const short8*)&Bsl[rb];
      }
    __syncthreads();                         // all reads done; buffers free
    if (kt + 1 < NT){
      const int kn = (kt + 1) << 6;
      #pragma unroll
      for (int u = 0; u < 4; u++){
        lds_dma16(Ah + aoff[u] + kn, &Ash[ldst[u]]);
        lds_dma16(Al + aoff[u] + kn, &Asl[ldst[u]]);
        lds_dma16(Bh + boff[u] + kn, &Bsh[ldst[u]]);
        lds_dma16(Bl + boff[u] + kn, &Bsl[ldst[u]]);
      }
    }
    __builtin_amdgcn_sched_barrier(0);
    #pragma unroll
    for (int ks = 0; ks < 2; ks++)
      #pragma unroll
      for (int i = 0; i < 4; i++)
        #pragma unroll
        for (int j = 0; j < 4; j++){
          acc[i][j] = mfma_bf16(afh[ks][i], bvh[ks][j], acc[i][j]);
          acc[i][j] = mfma_bf16(afh[ks][i], bvl[ks][j], acc[i][j]);
          acc[i][j] = mfma_bf16(afl[ks][i], bvh[ks][j], acc[i][j]);
        }
  }

  // fused xpos epilogue. col pairs (2ip, 2ip+1) sit in lanes (l, l^1).
  #pragma unroll
  for (int j = 0; j < 4; j++){
    const long n  = bn + wn*64 + j*16 + l15;
    const int  ip = (int)(n >> 1);
    const float lsv  = __logf((2.0f*ip + 409.6f) * (1.0f/1433.6f));
    const float invf = __expf(-(float)ip * (9.2103403720f/512.0f));  // 10000^(-ip/512)
    const float sgn  = (n & 1) ? 1.0f : -1.0f;
    #pragma unroll
    for (int i = 0; i < 4; i++){
      const long mb = bm + wm*64 + i*16 + kg*4;
      #pragma unroll
      for (int r = 0; r < 4; r++){
        float x = acc[i][j][r];
        float p = __shfl_xor(x, 1);
        const float fs = (float)((int)((mb + r) & 4095));
        const float scale = __expf(lsv * fs * (1.0f/512.0f));
        float sn, cs;
        __sincosf(fs * invf, &sn, &cs);
        sn *= scale; cs *= scale;
        C[(size_t)(mb + r) * N + n] = x*cs + sgn*(p*sn);
      }
    }
  }
}

// ---------------------------------------------------------------------------
// C(bf16) = A(f32) @ Bw(bf16)^T.  BM=128 x BN=256, BK=64. B double-buffered
// (DMA), A reg-staged (native bf16 cvt). GATE=1: fused z*silu epilogue.
// Measured R8: 58.5us, MfmaUtil 22%, VALUBusy 32%, 2 blocks/CU (reg-capped).
// ---------------------------------------------------------------------------
template<int GATE>
__global__ __launch_bounds__(256, 2)
void gemm_af32(const float* __restrict__ A, const unsigned short* __restrict__ Bw,
               unsigned short* __restrict__ C, int M, int N, int K,
               const float* __restrict__ zs, const float* __restrict__ zc)
{
  __shared__ __align__(16) short As[128*64];        // 16 KB
  __shared__ __align__(16) short Bs[2][256*64];     // 2 x 32 KB
  const int t = threadIdx.x, lane = t & 63;
  const int w = t >> 6, wm = w >> 1, wn = w & 1;
  const int l15 = lane & 15, kg = lane >> 4;
  const int sx = (l15 & 7) * 8;
  long bmi, bni; tile_remap(bmi, bni);
  const long bm = bmi * 128, bn = bni * 256;

  size_t boff[8]; int bdst[8];
  #pragma unroll
  for (int u = 0; u < 8; u++){
    const int cl = u*256 + t, row = cl >> 3, cr = cl & 7;
    boff[u] = (size_t)(bn + row) * K + (cr ^ (row & 7)) * 8;
    bdst[u] = cl * 8;
  }
  const int sr = t >> 3, sc8 = (t & 7) * 8;
  const int scx = sc8 ^ ((sr & 7) * 8);
  const float* pa[4]; short* la[4];
  #pragma unroll
  for (int u = 0; u < 4; u++){
    pa[u] = A + (bm + sr + u*32) * (size_t)K + sc8;
    la[u] = &As[(sr + u*32)*64 + scx];
  }

  floatx4 acc[4][8] = {};
  floatx4 cur[8];
  #pragma unroll
  for (int u = 0; u < 4; u++){
    cur[2*u]   = *(const floatx4*)(pa[u]);
    cur[2*u+1] = *(const floatx4*)(pa[u] + 4);
  }
  #pragma unroll
  for (int u = 0; u < 8; u++) lds_dma16(Bw + boff[u], &Bs[0][bdst[u]]);

  const int NT = K >> 6;
  int o = 0;
  for (int kt = 0; kt < NT; ++kt){
    __syncthreads();                       // B(kt)->Bs[o] landed; As reads done
    #pragma unroll
    for (int u = 0; u < 4; u++){           // ds_write A(kt) from cur
      short8 h;
      #pragma unroll
      for (int j = 0; j < 8; j++){
        float x = (j < 4) ? cur[2*u][j] : cur[2*u+1][j-4];
        h[j] = (short)f2b(x);
      }
      *(short8*)la[u] = h;
    }
    __syncthreads();                       // As visible; Bs[o^1] free
    const int kn = (kt + 1 < NT) ? ((kt + 1) << 6) : 0;
    if (kt + 1 < NT){
      #pragma unroll
      for (int u = 0; u < 8; u++) lds_dma16(Bw + boff[u] + kn, &Bs[o^1][bdst[u]]);
    }
    #pragma unroll
    for (int u = 0; u < 4; u++){           // cur <- A(kt+1), flies under MFMA
      cur[2*u]   = *(const floatx4*)(pa[u] + kn);
      cur[2*u+1] = *(const floatx4*)(pa[u] + kn + 4);
    }
    __builtin_amdgcn_sched_barrier(0);
    #pragma unroll
    for (int ks = 0; ks < 2; ks++){
      short8 af[4], bv[8];
      #pragma unroll
      for (int i = 0; i < 4; i++)
        af[i] = *(const short8*)&As[(wm*64 + i*16 + l15)*64 + ((ks*32 + kg*8) ^ sx)];
      #pragma unroll
      for (int j = 0; j < 8; j++)
        bv[j] = *(const short8*)&Bs[o][(wn*128 + j*16 + l15)*64 + ((ks*32 + kg*8) ^ sx)];
      #pragma unroll
      for (int i = 0; i < 4; i++)
        #pragma unroll
        for (int j = 0; j < 8; j++)
          acc[i][j] = mfma_bf16(af[i], bv[j], acc[i][j]);
    }
    o ^= 1;
  }

  if (GATE){
    #pragma unroll
    for (int i = 0; i < 4; i++){
      const long mb = bm + wm*64 + i*16 + kg*4;
      #pragma unroll
      for (int r = 0; r < 4; r++){
        const long row = mb + r;
        const int  ss  = (int)(row & 4095);
        const long bb  = row >> 12;
        const float* zr = (ss < 64) ? (zs + (((size_t)(bb*64 + ss)) << 10))
                                    : (zc + ((size_t)bb << 10));
        #pragma unroll
        for (int j = 0; j < 8; j++){
          const long n = bn + wn*128 + j*16 + l15;
          float g = acc[i][j][r] * zr[n];
          float sig = 1.0f / (1.0f + __expf(-g));
          C[(size_t)row * N + n] = f2b(g * sig);
        }
      }
    }
  } else {
    #pragma unroll
    for (int i = 0; i < 4; i++){
      const long mb = bm + wm*64 + i*16 + kg*4;
      #pragma unroll
      for (int j = 0; j < 8; j++){
        const long n = bn + wn*128 + j*16 + l15;
        #pragma unroll
        for (int r = 0; r < 4; r++)
          C[(size_t)(mb + r) * N + n] = f2b(acc[i][j][r]);
      }
    }
  }
}

// ---------------------------------------------------------------------------
// Q-path only: C(f32) = xpos( A(f32) @ B^T ) split-bf16 reg-staged.
// Grid (8,2) -> tile_remap identity. Gather r -> (r>>6)*4096 + (r&63).
// ---------------------------------------------------------------------------
template<int QG>
__global__ __launch_bounds__(256, 2)
void gemm_split(const float* __restrict__ A, const unsigned short* __restrict__ Bh,
                const unsigned short* __restrict__ Bl, float* __restrict__ C,
                int M, int N, int K)
{
  __shared__ __align__(16) short Ash[128*64];
  __shared__ __align__(16) short Asl[128*64];
  __shared__ __align__(16) short Bsh[128*64];
  __shared__ __align__(16) short Bsl[128*64];
  const int t    = threadIdx.x;
  const int lane = t & 63;
  const int w    = t >> 6, wm = w >> 1, wn = w & 1;
  const int l15  = lane & 15, kg = lane >> 4;
  const int sx   = (l15 & 7) * 8;
  long bmi, bni; tile_remap(bmi, bni);
  const long bm = bmi * 128, bn = bni * 128;

  const int sr = t >> 3, sc8 = (t & 7) * 8;
  const int scx = sc8 ^ ((sr & 7) * 8);
  const unsigned short *pbh[4], *pbl[4];
  const float* pa[4];
  short *lbh[4], *lbl[4], *lah[4], *lal[4];
  #pragma unroll
  for (int u = 0; u < 4; u++){
    pbh[u] = Bh + (bn + sr + u*32) * (size_t)K + scx;
    pbl[u] = Bl + (bn + sr + u*32) * (size_t)K + scx;
    long ar = bm + sr + u*32;
    if (QG) ar = (ar >> 6) * 4096 + (ar & 63);
    pa[u]  = A + ar * (size_t)K + sc8;
    lbh[u] = &Bsh[(sr + u*32)*64 + sc8];
    lbl[u] = &Bsl[(sr + u*32)*64 + sc8];
    lah[u] = &Ash[(sr + u*32)*64 + scx];
    lal[u] = &Asl[(sr + u*32)*64 + scx];
  }

  floatx4 acc[4][4] = {};
  floatx4 cur[8];
  #pragma unroll
  for (int u = 0; u < 4; u++){
    cur[2*u]   = *(const floatx4*)(pa[u]);
    cur[2*u+1] = *(const floatx4*)(pa[u] + 4);
  }
  #pragma unroll
  for (int u = 0; u < 4; u++){
    lds_dma16(pbh[u], lbh[u]);
    lds_dma16(pbl[u], lbl[u]);
  }

  const int NT = K >> 6;
  for (int kt = 0; kt < NT; ++kt){
    __syncthreads();
    #pragma unroll
    for (int u = 0; u < 4; u++){
      short8 h, l;
      #pragma unroll
      for (int j = 0; j < 8; j++){
        float x = (j < 4) ? cur[2*u][j] : cur[2*u+1][j-4];
        unsigned short hb = f2b(x);
        h[j] = (short)hb;
        l[j] = (short)f2b(x - b2f(hb));
      }
      *(short8*)lah[u] = h;
      *(short8*)lal[u] = l;
    }
    short8 bvh[2][4], bvl[2][4];
    #pragma unroll
    for (int ks = 0; ks < 2; ks++)
      #pragma unroll
      for (int i = 0; i < 4; i++){
        const int rb = (wn*64 + i*16 + l15)*64 + ((ks*32 + kg*8) ^ sx);
        bvh[ks][i] = *(const short8*)&Bsh[rb];
        bvl[ks][i] = *(const short8*)&Bsl[rb];
      }
    __syncthreads();
    const int kn = (kt + 1 < NT) ? ((kt + 1) << 6) : 0;
    if (kt + 1 < NT){
      #pragma unroll
      for (int u = 0; u < 4; u++){
        lds_dma16(pbh[u] + kn, lbh[u]);
        lds_dma16(pbl[u] + kn, lbl[u]);
      }
    }
    #pragma unroll
    for (int u = 0; u < 4; u++){
      cur[2*u]   = *(const floatx4*)(pa[u] + kn);
      cur[2*u+1] = *(const floatx4*)(pa[u] + kn + 4);
    }
    __builtin_amdgcn_sched_barrier(0);
    #pragma unroll
    for (int ks = 0; ks < 2; ks++){
      short8 afh[4], afl[4];
      #pragma unroll
      for (int i = 0; i < 4; i++){
        const int ra = (wm*64 + i*16 + l15)*64 + ((ks*32 + kg*8) ^ sx);
        afh[i] = *(const short8*)&Ash[ra];
        afl[i] = *(const short8*)&Asl[ra];
      }
      #pragma unroll
      for (int i = 0; i < 4; i++)
        #pragma unroll
        for (int j = 0; j < 4; j++){
          acc[i][j] = mfma_bf16(afh[i], bvh[ks][j], acc[i][j]);
          acc[i][j] = mfma_bf16(afh[i], bvl[ks][j], acc[i][j]);
          acc[i][j] = mfma_bf16(afl[i], bvh[ks][j], acc[i][j]);
        }
    }
  }

  const int smask = QG ? 63 : 4095;
  #pragma unroll
  for (int j = 0; j < 4; j++){
    const long n  = bn + wn*64 + j*16 + l15;
    const int  ip = (int)(n >> 1);
    const float lsv  = __logf((2.0f*ip + 409.6f) * (1.0f/1433.6f));
    const float invf = __expf(-(float)ip * (9.2103403720f/512.0f));
    const float sgn  = (n & 1) ? 1.0f : -1.0f;
    #pragma unroll
    for (int i = 0; i < 4; i++){
      const long mb = bm + wm*64 + i*16 + kg*4;
      #pragma unroll
      for (int r = 0; r < 4; r++){
        float x = acc[i][j][r];
        float p = __shfl_xor(x, 1);
        const float fs = (float)((int)((mb + r) & smask));
        const float scale = __expf(lsv * fs * (1.0f/512.0f));
        float sn, cs;
        __sincosf(fs * invf, &sn, &cs);
        sn *= scale; cs *= scale;
        C[(size_t)(mb + r) * N + n] = x*cs + sgn*(p*sn);
      }
    }
  }
}

// ---------------------------------------------------------------------------
// Split-precision projection: P[b*2][e][d'] += sum_s wxw[e,s]*X[b][s,d'].
// ---------------------------------------------------------------------------
__global__ __launch_bounds__(256, 2)
void proj_split(const float* __restrict__ X0, const unsigned short* __restrict__ wxh,
                const unsigned short* __restrict__ wxl, float* __restrict__ P)
{
  __shared__ __align__(16) short Wsh[64*32];
  __shared__ __align__(16) short Wsl[64*32];
  __shared__ __align__(16) short Xth[64*40];
  __shared__ __align__(16) short Xtl[64*40];
  const int t = threadIdx.x, w = t >> 6, lane = t & 63;
  const int l15 = lane & 15, kg = lane >> 4;
  const int d0 = blockIdx.x * 64;
  const int b  = blockIdx.y;
  const float* X = X0 + (size_t)b * 4096 * 1024;
  const int s0 = blockIdx.z * 512;
  const int ssr = t >> 3, ddr = (t & 7) * 8;
  floatx4 acc[4] = {};

  for (int kk = 0; kk < 512; kk += 32){
    const int s = s0 + kk;
    floatx4 x0 = *(const floatx4*)&X[(size_t)(s + ssr) * 1024 + d0 + ddr];
    floatx4 x1 = *(const floatx4*)&X[(size_t)(s + ssr) * 1024 + d0 + ddr + 4];
    __syncthreads();
    lds_dma16(&wxh[(size_t)(t >> 2) * 4096 + s + (t & 3) * 8], &Wsh[t*8]);
    lds_dma16(&wxl[(size_t)(t >> 2) * 4096 + s + (t & 3) * 8], &Wsl[t*8]);
    float xv[8] = {x0[0],x0[1],x0[2],x0[3],x1[0],x1[1],x1[2],x1[3]};
    #pragma unroll
    for (int j = 0; j < 8; j++){
      unsigned short hb = f2b(xv[j]);
      Xth[(ddr + j) * 40 + ssr] = (short)hb;
      Xtl[(ddr + j) * 40 + ssr] = (short)f2b(xv[j] - b2f(hb));
    }
    __syncthreads();
    short8 afh = *(const short8*)&Wsh[(w*16 + l15)*32 + kg*8];
    short8 afl = *(const short8*)&Wsl[(w*16 + l15)*32 + kg*8];
    #pragma unroll
    for (int j = 0; j < 4; j++){
      short8 bvh = *(const short8*)&Xth[(j*16 + l15)*40 + kg*8];
      short8 bvl = *(const short8*)&Xtl[(j*16 + l15)*40 + kg*8];
      acc[j] = mfma_bf16(afh, bvh, acc[j]);
      acc[j] = mfma_bf16(afh, bvl, acc[j]);
      acc[j] = mfma_bf16(afl, bvh, acc[j]);
    }
  }
  float* Pb = P + (size_t)(b*2) * 65536;
  #pragma unroll
  for (int j = 0; j < 4; j++)
    #pragma unroll
    for (int r = 0; r < 4; r++)
      atomicAdd(&Pb[(w*16 + kg*4 + r) * 1024 + d0 + j*16 + l15], acc[j][r]);
}

// ---------------------------------------------------------------------------
// bf16 projection for V: P[b*2+1][e][d'] += sum_s wxw_h[e,s]*X[b][s,d']
// ---------------------------------------------------------------------------
__global__ __launch_bounds__(256, 2)
void proj_bf16(const unsigned short* __restrict__ X0, const unsigned short* __restrict__ wxw_bf,
               float* __restrict__ P)
{
  __shared__ __align__(16) short Ws[64*32];
  __shared__ __align__(16) short Xt[64*40];
  const int t = threadIdx.x, w = t >> 6, lane = t & 63;
  const int l15 = lane & 15, kg = lane >> 4;
  const int d0 = blockIdx.x * 64;
  const int b  = blockIdx.y;
  const unsigned short* X = X0 + (size_t)b * 4096 * 1024;
  const int s0 = blockIdx.z * 512;
  const int ssr = t >> 3, ddr = (t & 7) * 8;
  floatx4 acc[4] = {};

  for (int kk = 0; kk < 512; kk += 32){
    const int s = s0 + kk;
    short8 xv = *(const short8*)&X[(size_t)(s + ssr) * 1024 + d0 + ddr];
    __syncthreads();
    lds_dma16(&wxw_bf[(size_t)(t >> 2) * 4096 + s + (t & 3) * 8], &Ws[t*8]);
    #pragma unroll
    for (int j = 0; j < 8; j++) Xt[(ddr + j) * 40 + ssr] = xv[j];
    __syncthreads();
    short8 af = *(const short8*)&Ws[(w*16 + l15)*32 + kg*8];
    #pragma unroll
    for (int j = 0; j < 4; j++){
      short8 bv = *(const short8*)&Xt[(j*16 + l15)*40 + kg*8];
      acc[j] = mfma_bf16(af, bv, acc[j]);
    }
  }
  float* Pb = P + (size_t)(b*2 + 1) * 65536;
  #pragma unroll
  for (int j = 0; j < 4; j++)
    #pragma unroll
    for (int r = 0; r < 4; r++)
      atomicAdd(&Pb[(w*16 + kg*4 + r) * 1024 + d0 + j*16 + l15], acc[j][r]);
}

// ---------------------------------------------------------------------------
// Per (b,h) attention + group norm. 256 threads: wave w owns e-quarter for
// scores and g-quarter for outputs; scores round-trip through LDS.
// Masked score entries are literal ZEROS (matches reference softmax).
// ---------------------------------------------------------------------------
__global__ __launch_bounds__(256)
void attn_kernel(const float* __restrict__ P, const float* __restrict__ Qx,
                 const float* __restrict__ wxb,
                 const float* __restrict__ gnw, const float* __restrict__ gnb,
                 float* __restrict__ zs, float* __restrict__ zc)
{
  __shared__ __align__(16) float kps[64*64];   // [e][d]
  __shared__ __align__(16) float vps[64*64];   // [e][f]
  __shared__ __align__(16) float scs[64*65];   // [e][s], stride 65
  __shared__ float pm[256];
  __shared__ float ym[64];
  const int t = threadIdx.x;
  const int w = t >> 6, s = t & 63;
  const int b = blockIdx.x >> 4, h = blockIdx.x & 15;
  const float* Pk = P + (size_t)(2*b) * 65536 + h*64;
  const float* Pv = Pk + 65536;

  {
    const int e = t >> 2, c = (t & 3) * 16;
    const float wb = wxb[e];
    #pragma unroll
    for (int j = 0; j < 4; j++){
      floatx4 kv = *(const floatx4*)&Pk[(size_t)e*1024 + c + 4*j];
      floatx4 vv = *(const floatx4*)&Pv[(size_t)e*1024 + c + 4*j];
      kv.x += wb; kv.y += wb; kv.z += wb; kv.w += wb;
      vv.x += wb; vv.y += wb; vv.z += wb; vv.w += wb;
      *(floatx4*)&kps[e*64 + c + 4*j] = kv;
      *(floatx4*)&vps[e*64 + c + 4*j] = vv;
    }
  }
  __syncthreads();

  float qf[64];
  const floatx4* q4 = (const floatx4*)(Qx + (size_t)(b*64 + s)*1024 + h*64);
  #pragma unroll
  for (int i = 0; i < 16; i++){
    floatx4 qq = q4[i];
    qf[4*i] = qq.x; qf[4*i+1] = qq.y; qf[4*i+2] = qq.z; qf[4*i+3] = qq.w;
  }

  #pragma unroll
  for (int eo = 0; eo < 16; eo++){
    const int e = w*16 + eo;
    const floatx4* kp4 = (const floatx4*)&kps[e*64];
    float dot = 0.f;
    #pragma unroll
    for (int d = 0; d < 16; d++){
      floatx4 kv = kp4[d];
      dot += qf[4*d]*kv.x + qf[4*d+1]*kv.y + qf[4*d+2]*kv.z + qf[4*d+3]*kv.w;
    }
    scs[e*65 + s] = dot;
  }
  {
    float am = 0.f;
    #pragma unroll
    for (int eo = 0; eo < 16; eo++) am += vps[(w*16 + eo)*64 + s];
    pm[t] = am;
  }
  __syncthreads();

  const float lg = -3.4657359028f - 0.1848392483f * (float)h;
  const float gamma = 1.0f - __expf(lg);
  float sc[64];
  #pragma unroll
  for (int e = 0; e < 64; e++) sc[e] = scs[e*65 + s];
  float dec = 1.0f;
  #pragma unroll
  for (int e = 0; e < 64; e++){
    bool on = (e >= s);
    sc[e] = on ? sc[e]*dec : 0.0f;
    if (on) dec *= gamma;
  }
  float mx = -1e30f;
  #pragma unroll
  for (int e = 0; e < 64; e++) mx = fmaxf(mx, sc[e]);
  float Z = 0.f;
  #pragma unroll
  for (int e = 0; e < 64; e++){ sc[e] = __expf(sc[e] - mx); Z += sc[e]; }
  const float rz = 1.0f / Z;

  #pragma unroll
  for (int go = 0; go < 4; go++){
    const int g = w*4 + go;
    floatx4 y = {0.f,0.f,0.f,0.f};
    #pragma unroll
    for (int e = 0; e < 64; e++){
      floatx4 vv = *(const floatx4*)&vps[e*64 + g*4];
      y += sc[e] * vv;
    }
    y *= rz;
    float mu = (y.x + y.y + y.z + y.w) * 0.25f;
    float a0 = y.x-mu, a1 = y.y-mu, a2 = y.z-mu, a3 = y.w-mu;
    float inv = rsqrtf((a0*a0 + a1*a1 + a2*a2 + a3*a3)*0.25f + 1e-5f);
    floatx4 o;
    o.x = a0*inv*gnw[g*4+0] + gnb[g*4+0];
    o.y = a1*inv*gnw[g*4+1] + gnb[g*4+1];
    o.z = a2*inv*gnw[g*4+2] + gnb[g*4+2];
    o.w = a3*inv*gnw[g*4+3] + gnb[g*4+3];
    *(floatx4*)&zs[(size_t)(b*64 + s)*1024 + h*64 + g*4] = o;
  }

  if (w == 0)
    ym[s] = (pm[s] + pm[64+s] + pm[128+s] + pm[192+s]) * (1.0f/64.0f);
  __syncthreads();
  if (t < 16){
    float a0 = ym[t*4], a1 = ym[t*4+1], a2 = ym[t*4+2], a3 = ym[t*4+3];
    float mu = (a0+a1+a2+a3)*0.25f;
    a0 -= mu; a1 -= mu; a2 -= mu; a3 -= mu;
    float inv = rsqrtf((a0*a0+a1*a1+a2*a2+a3*a3)*0.25f + 1e-5f);
    zc[(size_t)b*1024 + h*64 + t*4+0] = a0*inv*gnw[t*4+0] + gnb[t*4+0];
    zc[(size_t)b*1024 + h*64 + t*4+1] = a1*inv*gnw[t*4+1] + gnb[t*4+1];
    zc[(size_t)b*1024 + h*64 + t*4+2] = a2*inv*gnw[t*4+2] + gnb[t*4+2];
    zc[(size_t)b*1024 + h*64 + t*4+3] = a3*inv*gnw[t*4+3] + gnb[t*4+3];
  }
}

// ---------------------------------------------------------------------------
// C(f32) = A(bf16) @ B(bf16)^T — final GEMM. BK=64, both DMA, swizzled LDS,
// XCD remap, 3 blocks/CU. 128x128 kept (m105: 128x256 regresses pure-DMA).
// ---------------------------------------------------------------------------
__global__ __launch_bounds__(256, 3)
void gemm_bt(const unsigned short* __restrict__ A, const unsigned short* __restrict__ Bw,
             float* __restrict__ C, int M, int N, int K)
{
  __shared__ __align__(16) short As[128*64];
  __shared__ __align__(16) short Bs[128*64];
  const int t    = threadIdx.x;
  const int lane = t & 63;
  const int w    = t >> 6, wm = w >> 1, wn = w & 1;
  const int l15  = lane & 15, kg = lane >> 4;
  const int sx   = (l15 & 7) * 8;
  long bmi, bni; tile_remap(bmi, bni);
  const long bm = bmi * 128, bn = bni * 128;

  const int sr = t >> 3, sc8 = (t & 7) * 8;
  const int scx = sc8 ^ ((sr & 7) * 8);
  const unsigned short *pa[4], *pb[4];
  short *la[4], *lb[4];
  #pragma unroll
  for (int u = 0; u < 4; u++){
    pa[u] = A  + (bm + sr + u*32) * (size_t)K + scx;
    pb[u] = Bw + (bn + sr + u*32) * (size_t)K + scx;
    la[u] = &As[(sr + u*32)*64 + sc8];
    lb[u] = &Bs[(sr + u*32)*64 + sc8];
  }

  floatx4 acc[4][4] = {};

  #pragma unroll
  for (int u = 0; u < 4; u++){
    lds_dma16(pa[u], la[u]);
    lds_dma16(pb[u], lb[u]);
  }

  const int NT = K >> 6;
  for (int kt = 0; kt < NT; ++kt){
    __syncthreads();
    short8 af[2][4], bv[2][4];
    #pragma unroll
    for (int ks = 0; ks < 2; ks++)
      #pragma unroll
      for (int i = 0; i < 4; i++){
        af[ks][i] = *(const short8*)&As[(wm*64 + i*16 + l15)*64 + ((ks*32 + kg*8) ^ sx)];
        bv[ks][i] = *(const short8*)&Bs[(wn*64 + i*16 + l15)*64 + ((ks*32 + kg*8) ^ sx)];
      }
    __syncthreads();
    if (kt + 1 < NT){
      const int kn = (kt + 1) << 6;
      #pragma unroll
      for (int u = 0; u < 4; u++){
        lds_dma16(pa[u] + kn, la[u]);
        lds_dma16(pb[u] + kn, lb[u]);
      }
    }
    __builtin_amdgcn_sched_barrier(0);
    #pragma unroll
    for (int ks = 0; ks < 2; ks++)
      #pragma unroll
      for (int i = 0; i < 4; i++)
        #pragma unroll
        for (int j = 0; j < 4; j++)
          acc[i][j] = mfma_bf16(af[ks][i], bv[ks][j], acc[i][j]);
  }

  #pragma unroll
  for (int i = 0; i < 4; i++){
    const long mb = bm + wm*64 + i*16 + kg*4;
    #pragma unroll
    for (int j = 0; j < 4; j++){
      const long n = bn + wn*64 + j*16 + l15;
      #pragma unroll
      for (int r = 0; r < 4; r++)
        C[(size_t)(mb + r) * N + n] = acc[i][j][r];
    }
  }
}

// ---------------------------------------------------------------------------
extern "C" void kernel_launch(void* const* d_in, const int* in_sizes, int n_in,
                              void* d_out, int out_size, void* d_ws, size_t ws_size,
                              hipStream_t stream)
{
  const float* q   = (const float*)d_in[0];
  const float* k   = (const float*)d_in[1];
  const float* v   = (const float*)d_in[2];
  const float* wq  = (const float*)d_in[3];
  const float* wk  = (const float*)d_in[4];
  const float* wv  = (const float*)d_in[5];
  const float* wo  = (const float*)d_in[6];
  const float* wg  = (const float*)d_in[7];
  const float* wxw = (const float*)d_in[8];
  const float* wxb = (const float*)d_in[9];
  const float* gnw = (const float*)d_in[10];
  const float* gnb = (const float*)d_in[11];

  // ws layout (47.2 MB). d_out (f32, 64 MB) doubles as Kx f32 scratch.
  // A0 (32 MB) triple-duty: {kh|kl half-passes} -> Vx bf16 -> Agate bf16.
  char* ws = (char*)d_ws;
  unsigned short* A0   = (unsigned short*)(ws);             // 32 MB
  unsigned short* wh   = (unsigned short*)(ws + 33554432);  // 2 MB: wk_h -> wq_h
  unsigned short* wl   = (unsigned short*)(ws + 35651584);  // 2 MB: wk_l -> wq_l
  unsigned short* wAbf = (unsigned short*)(ws + 37748736);  // 2 MB: wv -> wo
  unsigned short* wgbf = (unsigned short*)(ws + 39845888);  // 2 MB
  unsigned short* wxh  = (unsigned short*)(ws + 41943040);  // 512 KB
  unsigned short* wxl  = (unsigned short*)(ws + 42467328);  // 512 KB
  float*          P    = (float*)(ws + 42991616);           // 2 MB
  float*          zs   = (float*)(ws + 45088768);           // 1 MB
  float*          zc   = (float*)(ws + 46137344);           // 16 KB
  float*          Qx   = (float*)(ws + 46153728);           // 1 MB
  float*          Kx   = (float*)d_out;                     // 64 MB f32 scratch

  const int M = 16384, N = 1024, K = 1024;
  dim3 blk(256);

  // fused weight prep (wk-split | wxw-split | wv | wg) — was 4 launches
  wprep<<<1664, blk, 0, stream>>>(wk, wh, wl, wxw, wxh, wxl, wv, wAbf, wg, wgbf);
  hipMemsetAsync(P, 0, 2097152, stream);

  // K path: pre-split k (half-M passes through A0), all-DMA 3-term GEMM
  // (xpos fused; row offset 8192 is a multiple of 4096 so position math holds)
  for (int p = 0; p < 2; p++){
    cvt_split<<<4096, blk, 0, stream>>>(k + (size_t)p*8388608, A0, A0 + 8388608, 1048576);
    gemm_split3<<<dim3(8,64), blk, 0, stream>>>(A0, A0 + 8388608, wh, wl,
                                                Kx + (size_t)p*8388608, 8192, N, K);
  }
  proj_split<<<dim3(16,4,8), blk, 0, stream>>>(Kx, wxh, wxl, P);

  // V path: v @ wv^T -> A0 bf16 (BN=256), proj
  gemm_af32<0><<<dim3(4,128), blk, 0, stream>>>(v, wAbf, A0, M, N, K, nullptr, nullptr);
  // fused: wq-split (wk dead) + wo-cvt (wv dead after af32<0>) — was 2 launches
  wprep2<<<1024, blk, 0, stream>>>(wq, wh, wl, wo, wAbf);
  proj_bf16<<<dim3(16,4,8), blk, 0, stream>>>(A0, wxh, P);

  // Q path: gather 64 rows/batch, xpos fused, attention
  gemm_split<1><<<dim3(8,2), blk, 0, stream>>>(q, wh, wl, Qx, 256, N, K);
  attn_kernel<<<64, 256, 0, stream>>>(P, Qx, wxb, gnw, gnb, zs, zc);

  // Gate path: G = silu((q @ wg^T) * z) fused in epilogue -> A0, final GEMM
  gemm_af32<1><<<dim3(4,128), blk, 0, stream>>>(q, wgbf, A0, M, N, K, zs, zc);
  gemm_bt<<<dim3(8,128), blk, 0, stream>>>(A0, wAbf, (float*)d_out, M, N, K);
}

// Round 10
// 515.975 us; speedup vs baseline: 1.2294x; 1.0623x over previous
//
#include <hip/hip_runtime.h>
#include <hip/hip_bf16.h>

#define DEVI __device__ __forceinline__

typedef __attribute__((ext_vector_type(8))) short  short8;
typedef __attribute__((ext_vector_type(4))) float  floatx4;
typedef __attribute__((ext_vector_type(8))) __bf16 bf16x8;

DEVI float b2f(unsigned short u){ union{unsigned int i; float f;} x; x.i=((unsigned int)u)<<16; return x.f; }
// Native bf16 convert (RNE) -> compiler emits v_cvt_pk_bf16_f32 for pairs.
DEVI unsigned short f2b(float f){
  return __builtin_bit_cast(unsigned short, (__bf16)f);
}

DEVI void lds_dma16(const void* g, void* l){
  __builtin_amdgcn_global_load_lds((const __attribute__((address_space(1))) void*)g,
                                   (__attribute__((address_space(3))) void*)l, 16, 0, 0);
}

DEVI floatx4 mfma_bf16(short8 a, short8 b, floatx4 c){
  return __builtin_amdgcn_mfma_f32_16x16x32_bf16(
      __builtin_bit_cast(bf16x8, a), __builtin_bit_cast(bf16x8, b), c, 0, 0, 0);
}

// XCD-chunked tile remap (T1), generalized. Verified R4: FETCH 266->65.6MB.
DEVI void tile_remap(long& bmi, long& bni){
  const int bx = blockIdx.x, by = blockIdx.y;
  if ((gridDim.y & 7) == 0 && gridDim.y >= 8){
    const int flat = bx + gridDim.x * by;
    const int xcd  = flat & 7;
    const int idx  = flat >> 3;
    bni = (long)(idx % gridDim.x);
    bmi = (long)(xcd * (gridDim.y >> 3) + idx / gridDim.x);
  } else {
    bni = bx; bmi = by;
  }
}

// LDS swizzle (both-sides XOR, rule 21), verified 0 bank conflicts R3-R9.

// ---------------------------------------------------------------------------
// elementwise conversion bodies
// ---------------------------------------------------------------------------
DEVI void cvt_body(const float* __restrict__ src, unsigned short* __restrict__ dst, int i, int n8)
{
  if (i >= n8) return;
  floatx4 a = ((const floatx4*)src)[2*(size_t)i];
  floatx4 b = ((const floatx4*)src)[2*(size_t)i + 1];
  short8 o;
  o[0]=(short)f2b(a[0]); o[1]=(short)f2b(a[1]); o[2]=(short)f2b(a[2]); o[3]=(short)f2b(a[3]);
  o[4]=(short)f2b(b[0]); o[5]=(short)f2b(b[1]); o[6]=(short)f2b(b[2]); o[7]=(short)f2b(b[3]);
  *(short8*)&dst[(size_t)i*8] = o;
}

DEVI void cvt_split_body(const float* __restrict__ src, unsigned short* __restrict__ dh,
                         unsigned short* __restrict__ dl, int i, int n8)
{
  if (i >= n8) return;
  floatx4 a = ((const floatx4*)src)[2*(size_t)i];
  floatx4 b = ((const floatx4*)src)[2*(size_t)i + 1];
  short8 h, l;
  #pragma unroll
  for (int j = 0; j < 8; j++){
    float x = (j < 4) ? a[j] : b[j-4];
    unsigned short hb = f2b(x);
    h[j] = (short)hb;
    l[j] = (short)f2b(x - b2f(hb));
  }
  *(short8*)&dh[(size_t)i*8] = h;
  *(short8*)&dl[(size_t)i*8] = l;
}

// f32 -> (hi,lo) bf16 split, standalone (K-path pass 1)
__global__ void cvt_split(const float* __restrict__ src, unsigned short* __restrict__ dh,
                          unsigned short* __restrict__ dl, int n8)
{
  cvt_split_body(src, dh, dl, blockIdx.x * 256 + threadIdx.x, n8);
}

// Fused prep: wk-split | wxw-split | wv-cvt | wg-cvt | P-zero | k-pass0-split
__global__ void wprep(const float* __restrict__ wk, unsigned short* __restrict__ wh,
                      unsigned short* __restrict__ wl,
                      const float* __restrict__ wxw, unsigned short* __restrict__ wxh,
                      unsigned short* __restrict__ wxl,
                      const float* __restrict__ wv, unsigned short* __restrict__ wvb,
                      const float* __restrict__ wg, unsigned short* __restrict__ wgb,
                      float* __restrict__ P,
                      const float* __restrict__ k0, unsigned short* __restrict__ kh,
                      unsigned short* __restrict__ kl)
{
  const int blk = blockIdx.x, t = threadIdx.x;
  if (blk < 512)        cvt_split_body(wk,  wh,  wl,  blk*256 + t,        131072);
  else if (blk < 640)   cvt_split_body(wxw, wxh, wxl, (blk-512)*256 + t,  32768);
  else if (blk < 1152)  cvt_body(wv, wvb, (blk-640)*256 + t,  131072);
  else if (blk < 1664)  cvt_body(wg, wgb, (blk-1152)*256 + t, 131072);
  else if (blk < 1920){
    const int i = (blk-1664)*256 + t;                 // 65536 threads x 8 f32
    floatx4 z = {0.f,0.f,0.f,0.f};
    ((floatx4*)P)[2*(size_t)i]     = z;
    ((floatx4*)P)[2*(size_t)i + 1] = z;
  } else                cvt_split_body(k0, kh, kl, (blk-1920)*256 + t, 1048576);
}

// Fused: wq-split + wo-cvt
__global__ void wprep2(const float* __restrict__ wq, unsigned short* __restrict__ wh,
                       unsigned short* __restrict__ wl,
                       const float* __restrict__ wo, unsigned short* __restrict__ wob)
{
  const int blk = blockIdx.x, t = threadIdx.x;
  if (blk < 512) cvt_split_body(wq, wh, wl, blk*256 + t, 131072);
  else           cvt_body(wo, wob, (blk-512)*256 + t, 131072);
}

// ---------------------------------------------------------------------------
// C(f32) = xpos( Ahl @ Bhl^T ) 3-term, all four streams pre-split bf16 and
// DMA-staged. 128x128, BK=64, swizzled LDS, XCD remap. ~930 TF measured (R8).
// Row offset of C must be a multiple of 4096 so position = local row & 4095.
// ---------------------------------------------------------------------------
__global__ __launch_bounds__(256, 2)
void gemm_split3(const unsigned short* __restrict__ Ah, const unsigned short* __restrict__ Al,
                 const unsigned short* __restrict__ Bh, const unsigned short* __restrict__ Bl,
                 float* __restrict__ C, int M, int N, int K)
{
  __shared__ __align__(16) short Ash[128*64];
  __shared__ __align__(16) short Asl[128*64];
  __shared__ __align__(16) short Bsh[128*64];
  __shared__ __align__(16) short Bsl[128*64];
  const int t = threadIdx.x, lane = t & 63;
  const int w = t >> 6, wm = w >> 1, wn = w & 1;
  const int l15 = lane & 15, kg = lane >> 4;
  const int sx = (l15 & 7) * 8;
  long bmi, bni; tile_remap(bmi, bni);
  const long bm = bmi * 128, bn = bni * 128;

  size_t aoff[4], boff[4]; int ldst[4];
  #pragma unroll
  for (int u = 0; u < 4; u++){
    const int cl = u*256 + t, row = cl >> 3, cr = cl & 7;
    const int csrc = (cr ^ (row & 7)) * 8;
    aoff[u] = (size_t)(bm + row) * K + csrc;
    boff[u] = (size_t)(bn + row) * K + csrc;
    ldst[u] = cl * 8;
  }

  floatx4 acc[4][4] = {};
  #pragma unroll
  for (int u = 0; u < 4; u++){
    lds_dma16(Ah + aoff[u], &Ash[ldst[u]]);
    lds_dma16(Al + aoff[u], &Asl[ldst[u]]);
    lds_dma16(Bh + boff[u], &Bsh[ldst[u]]);
    lds_dma16(Bl + boff[u], &Bsl[ldst[u]]);
  }

  const int NT = K >> 6;
  for (int kt = 0; kt < NT; ++kt){
    __syncthreads();                         // stage(kt) landed
    short8 afh[2][4], afl[2][4], bvh[2][4], bvl[2][4];
    #pragma unroll
    for (int ks = 0; ks < 2; ks++)
      #pragma unroll
      for (int i = 0; i < 4; i++){
        const int ra = (wm*64 + i*16 + l15)*64 + ((ks*32 + kg*8) ^ sx);
        const int rb = (wn*64 + i*16 + l15)*64 + ((ks*32 + kg*8) ^ sx);
        afh[ks][i] = *(const short8*)&Ash[ra];
        afl[ks][i] = *(const short8*)&Asl[ra];
        bvh[ks][i] = *(const short8*)&Bsh[rb];
        bvl[ks][i] = *(const short8*)&Bsl[rb];
      }
    __syncthreads();                         // all reads done; buffers free
    if (kt + 1 < NT){
      const int kn = (kt + 1) << 6;
      #pragma unroll
      for (int u = 0; u < 4; u++){
        lds_dma16(Ah + aoff[u] + kn, &Ash[ldst[u]]);
        lds_dma16(Al + aoff[u] + kn, &Asl[ldst[u]]);
        lds_dma16(Bh + boff[u] + kn, &Bsh[ldst[u]]);
        lds_dma16(Bl + boff[u] + kn, &Bsl[ldst[u]]);
      }
    }
    __builtin_amdgcn_sched_barrier(0);
    #pragma unroll
    for (int ks = 0; ks < 2; ks++)
      #pragma unroll
      for (int i = 0; i < 4; i++)
        #pragma unroll
        for (int j = 0; j < 4; j++){
          acc[i][j] = mfma_bf16(afh[ks][i], bvh[ks][j], acc[i][j]);
          acc[i][j] = mfma_bf16(afh[ks][i], bvl[ks][j], acc[i][j]);
          acc[i][j] = mfma_bf16(afl[ks][i], bvh[ks][j], acc[i][j]);
        }
  }

  // fused xpos epilogue. col pairs (2ip, 2ip+1) sit in lanes (l, l^1).
  #pragma unroll
  for (int j = 0; j < 4; j++){
    const long n  = bn + wn*64 + j*16 + l15;
    const int  ip = (int)(n >> 1);
    const float lsv  = __logf((2.0f*ip + 409.6f) * (1.0f/1433.6f));
    const float invf = __expf(-(float)ip * (9.2103403720f/512.0f));  // 10000^(-ip/512)
    const float sgn  = (n & 1) ? 1.0f : -1.0f;
    #pragma unroll
    for (int i = 0; i < 4; i++){
      const long mb = bm + wm*64 + i*16 + kg*4;
      #pragma unroll
      for (int r = 0; r < 4; r++){
        float x = acc[i][j][r];
        float p = __shfl_xor(x, 1);
        const float fs = (float)((int)((mb + r) & 4095));
        const float scale = __expf(lsv * fs * (1.0f/512.0f));
        float sn, cs;
        __sincosf(fs * invf, &sn, &cs);
        sn *= scale; cs *= scale;
        C[(size_t)(mb + r) * N + n] = x*cs + sgn*(p*sn);
      }
    }
  }
}

// ---------------------------------------------------------------------------
// C(bf16) = A(f32) @ Bw(bf16)^T.  BM=128 x BN=256, BK=64. B double-buffered
// (DMA), A reg-staged (native bf16 cvt). GATE=1: fused z*silu epilogue.
// ---------------------------------------------------------------------------
template<int GATE>
__global__ __launch_bounds__(256, 2)
void gemm_af32(const float* __restrict__ A, const unsigned short* __restrict__ Bw,
               unsigned short* __restrict__ C, int M, int N, int K,
               const float* __restrict__ zs, const float* __restrict__ zc)
{
  __shared__ __align__(16) short As[128*64];        // 16 KB
  __shared__ __align__(16) short Bs[2][256*64];     // 2 x 32 KB
  const int t = threadIdx.x, lane = t & 63;
  const int w = t >> 6, wm = w >> 1, wn = w & 1;
  const int l15 = lane & 15, kg = lane >> 4;
  const int sx = (l15 & 7) * 8;
  long bmi, bni; tile_remap(bmi, bni);
  const long bm = bmi * 128, bn = bni * 256;

  size_t boff[8]; int bdst[8];
  #pragma unroll
  for (int u = 0; u < 8; u++){
    const int cl = u*256 + t, row = cl >> 3, cr = cl & 7;
    boff[u] = (size_t)(bn + row) * K + (cr ^ (row & 7)) * 8;
    bdst[u] = cl * 8;
  }
  const int sr = t >> 3, sc8 = (t & 7) * 8;
  const int scx = sc8 ^ ((sr & 7) * 8);
  const float* pa[4]; short* la[4];
  #pragma unroll
  for (int u = 0; u < 4; u++){
    pa[u] = A + (bm + sr + u*32) * (size_t)K + sc8;
    la[u] = &As[(sr + u*32)*64 + scx];
  }

  floatx4 acc[4][8] = {};
  floatx4 cur[8];
  #pragma unroll
  for (int u = 0; u < 4; u++){
    cur[2*u]   = *(const floatx4*)(pa[u]);
    cur[2*u+1] = *(const floatx4*)(pa[u] + 4);
  }
  #pragma unroll
  for (int u = 0; u < 8; u++) lds_dma16(Bw + boff[u], &Bs[0][bdst[u]]);

  const int NT = K >> 6;
  int o = 0;
  for (int kt = 0; kt < NT; ++kt){
    __syncthreads();                       // B(kt)->Bs[o] landed; As reads done
    #pragma unroll
    for (int u = 0; u < 4; u++){           // ds_write A(kt) from cur
      short8 h;
      #pragma unroll
      for (int j = 0; j < 8; j++){
        float x = (j < 4) ? cur[2*u][j] : cur[2*u+1][j-4];
        h[j] = (short)f2b(x);
      }
      *(short8*)la[u] = h;
    }
    __syncthreads();                       // As visible; Bs[o^1] free
    const int kn = (kt + 1 < NT) ? ((kt + 1) << 6) : 0;
    if (kt + 1 < NT){
      #pragma unroll
      for (int u = 0; u < 8; u++) lds_dma16(Bw + boff[u] + kn, &Bs[o^1][bdst[u]]);
    }
    #pragma unroll
    for (int u = 0; u < 4; u++){           // cur <- A(kt+1), flies under MFMA
      cur[2*u]   = *(const floatx4*)(pa[u] + kn);
      cur[2*u+1] = *(const floatx4*)(pa[u] + kn + 4);
    }
    __builtin_amdgcn_sched_barrier(0);
    #pragma unroll
    for (int ks = 0; ks < 2; ks++){
      short8 af[4], bv[8];
      #pragma unroll
      for (int i = 0; i < 4; i++)
        af[i] = *(const short8*)&As[(wm*64 + i*16 + l15)*64 + ((ks*32 + kg*8) ^ sx)];
      #pragma unroll
      for (int j = 0; j < 8; j++)
        bv[j] = *(const short8*)&Bs[o][(wn*128 + j*16 + l15)*64 + ((ks*32 + kg*8) ^ sx)];
      #pragma unroll
      for (int i = 0; i < 4; i++)
        #pragma unroll
        for (int j = 0; j < 8; j++)
          acc[i][j] = mfma_bf16(af[i], bv[j], acc[i][j]);
    }
    o ^= 1;
  }

  if (GATE){
    #pragma unroll
    for (int i = 0; i < 4; i++){
      const long mb = bm + wm*64 + i*16 + kg*4;
      #pragma unroll
      for (int r = 0; r < 4; r++){
        const long row = mb + r;
        const int  ss  = (int)(row & 4095);
        const long bb  = row >> 12;
        const float* zr = (ss < 64) ? (zs + (((size_t)(bb*64 + ss)) << 10))
                                    : (zc + ((size_t)bb << 10));
        #pragma unroll
        for (int j = 0; j < 8; j++){
          const long n = bn + wn*128 + j*16 + l15;
          float g = acc[i][j][r] * zr[n];
          float sig = 1.0f / (1.0f + __expf(-g));
          C[(size_t)row * N + n] = f2b(g * sig);
        }
      }
    }
  } else {
    #pragma unroll
    for (int i = 0; i < 4; i++){
      const long mb = bm + wm*64 + i*16 + kg*4;
      #pragma unroll
      for (int j = 0; j < 8; j++){
        const long n = bn + wn*128 + j*16 + l15;
        #pragma unroll
        for (int r = 0; r < 4; r++)
          C[(size_t)(mb + r) * N + n] = f2b(acc[i][j][r]);
      }
    }
  }
}

// ---------------------------------------------------------------------------
// Q-path only: C(f32) = xpos( A(f32) @ B^T ) split-bf16 reg-staged.
// Grid (8,2) -> tile_remap identity. Gather r -> (r>>6)*4096 + (r&63).
// ---------------------------------------------------------------------------
template<int QG>
__global__ __launch_bounds__(256, 2)
void gemm_split(const float* __restrict__ A, const unsigned short* __restrict__ Bh,
                const unsigned short* __restrict__ Bl, float* __restrict__ C,
                int M, int N, int K)
{
  __shared__ __align__(16) short Ash[128*64];
  __shared__ __align__(16) short Asl[128*64];
  __shared__ __align__(16) short Bsh[128*64];
  __shared__ __align__(16) short Bsl[128*64];
  const int t    = threadIdx.x;
  const int lane = t & 63;
  const int w    = t >> 6, wm = w >> 1, wn = w & 1;
  const int l15  = lane & 15, kg = lane >> 4;
  const int sx   = (l15 & 7) * 8;
  long bmi, bni; tile_remap(bmi, bni);
  const long bm = bmi * 128, bn = bni * 128;

  const int sr = t >> 3, sc8 = (t & 7) * 8;
  const int scx = sc8 ^ ((sr & 7) * 8);
  const unsigned short *pbh[4], *pbl[4];
  const float* pa[4];
  short *lbh[4], *lbl[4], *lah[4], *lal[4];
  #pragma unroll
  for (int u = 0; u < 4; u++){
    pbh[u] = Bh + (bn + sr + u*32) * (size_t)K + scx;
    pbl[u] = Bl + (bn + sr + u*32) * (size_t)K + scx;
    long ar = bm + sr + u*32;
    if (QG) ar = (ar >> 6) * 4096 + (ar & 63);
    pa[u]  = A + ar * (size_t)K + sc8;
    lbh[u] = &Bsh[(sr + u*32)*64 + sc8];
    lbl[u] = &Bsl[(sr + u*32)*64 + sc8];
    lah[u] = &Ash[(sr + u*32)*64 + scx];
    lal[u] = &Asl[(sr + u*32)*64 + scx];
  }

  floatx4 acc[4][4] = {};
  floatx4 cur[8];
  #pragma unroll
  for (int u = 0; u < 4; u++){
    cur[2*u]   = *(const floatx4*)(pa[u]);
    cur[2*u+1] = *(const floatx4*)(pa[u] + 4);
  }
  #pragma unroll
  for (int u = 0; u < 4; u++){
    lds_dma16(pbh[u], lbh[u]);
    lds_dma16(pbl[u], lbl[u]);
  }

  const int NT = K >> 6;
  for (int kt = 0; kt < NT; ++kt){
    __syncthreads();
    #pragma unroll
    for (int u = 0; u < 4; u++){
      short8 h, l;
      #pragma unroll
      for (int j = 0; j < 8; j++){
        float x = (j < 4) ? cur[2*u][j] : cur[2*u+1][j-4];
        unsigned short hb = f2b(x);
        h[j] = (short)hb;
        l[j] = (short)f2b(x - b2f(hb));
      }
      *(short8*)lah[u] = h;
      *(short8*)lal[u] = l;
    }
    short8 bvh[2][4], bvl[2][4];
    #pragma unroll
    for (int ks = 0; ks < 2; ks++)
      #pragma unroll
      for (int i = 0; i < 4; i++){
        const int rb = (wn*64 + i*16 + l15)*64 + ((ks*32 + kg*8) ^ sx);
        bvh[ks][i] = *(const short8*)&Bsh[rb];
        bvl[ks][i] = *(const short8*)&Bsl[rb];
      }
    __syncthreads();
    const int kn = (kt + 1 < NT) ? ((kt + 1) << 6) : 0;
    if (kt + 1 < NT){
      #pragma unroll
      for (int u = 0; u < 4; u++){
        lds_dma16(pbh[u] + kn, lbh[u]);
        lds_dma16(pbl[u] + kn, lbl[u]);
      }
    }
    #pragma unroll
    for (int u = 0; u < 4; u++){
      cur[2*u]   = *(const floatx4*)(pa[u] + kn);
      cur[2*u+1] = *(const floatx4*)(pa[u] + kn + 4);
    }
    __builtin_amdgcn_sched_barrier(0);
    #pragma unroll
    for (int ks = 0; ks < 2; ks++){
      short8 afh[4], afl[4];
      #pragma unroll
      for (int i = 0; i < 4; i++){
        const int ra = (wm*64 + i*16 + l15)*64 + ((ks*32 + kg*8) ^ sx);
        afh[i] = *(const short8*)&Ash[ra];
        afl[i] = *(const short8*)&Asl[ra];
      }
      #pragma unroll
      for (int i = 0; i < 4; i++)
        #pragma unroll
        for (int j = 0; j < 4; j++){
          acc[i][j] = mfma_bf16(afh[i], bvh[ks][j], acc[i][j]);
          acc[i][j] = mfma_bf16(afh[i], bvl[ks][j], acc[i][j]);
          acc[i][j] = mfma_bf16(afl[i], bvh[ks][j], acc[i][j]);
        }
    }
  }

  const int smask = QG ? 63 : 4095;
  #pragma unroll
  for (int j = 0; j < 4; j++){
    const long n  = bn + wn*64 + j*16 + l15;
    const int  ip = (int)(n >> 1);
    const float lsv  = __logf((2.0f*ip + 409.6f) * (1.0f/1433.6f));
    const float invf = __expf(-(float)ip * (9.2103403720f/512.0f));
    const float sgn  = (n & 1) ? 1.0f : -1.0f;
    #pragma unroll
    for (int i = 0; i < 4; i++){
      const long mb = bm + wm*64 + i*16 + kg*4;
      #pragma unroll
      for (int r = 0; r < 4; r++){
        float x = acc[i][j][r];
        float p = __shfl_xor(x, 1);
        const float fs = (float)((int)((mb + r) & smask));
        const float scale = __expf(lsv * fs * (1.0f/512.0f));
        float sn, cs;
        __sincosf(fs * invf, &sn, &cs);
        sn *= scale; cs *= scale;
        C[(size_t)(mb + r) * N + n] = x*cs + sgn*(p*sn);
      }
    }
  }
}

// ---------------------------------------------------------------------------
// Projection bodies (shared-LDS fused launch).
// z<8: split-precision K-proj from Kx f32; z>=8: bf16 V-proj from Vx bf16.
// ---------------------------------------------------------------------------
DEVI void proj_split_body(const float* __restrict__ X0, const unsigned short* __restrict__ wxh,
                          const unsigned short* __restrict__ wxl, float* __restrict__ P,
                          char* smem, int d0, int b, int s0)
{
  short* Wsh = (short*)smem;            // 4096 B
  short* Wsl = (short*)(smem + 4096);   // 4096 B
  short* Xth = (short*)(smem + 8192);   // 5120 B
  short* Xtl = (short*)(smem + 13312);  // 5120 B
  const int t = threadIdx.x, w = t >> 6, lane = t & 63;
  const int l15 = lane & 15, kg = lane >> 4;
  const float* X = X0 + (size_t)b * 4096 * 1024;
  const int ssr = t >> 3, ddr = (t & 7) * 8;
  floatx4 acc[4] = {};

  for (int kk = 0; kk < 512; kk += 32){
    const int s = s0 + kk;
    floatx4 x0 = *(const floatx4*)&X[(size_t)(s + ssr) * 1024 + d0 + ddr];
    floatx4 x1 = *(const floatx4*)&X[(size_t)(s + ssr) * 1024 + d0 + ddr + 4];
    __syncthreads();
    lds_dma16(&wxh[(size_t)(t >> 2) * 4096 + s + (t & 3) * 8], &Wsh[t*8]);
    lds_dma16(&wxl[(size_t)(t >> 2) * 4096 + s + (t & 3) * 8], &Wsl[t*8]);
    float xv[8] = {x0[0],x0[1],x0[2],x0[3],x1[0],x1[1],x1[2],x1[3]};
    #pragma unroll
    for (int j = 0; j < 8; j++){
      unsigned short hb = f2b(xv[j]);
      Xth[(ddr + j) * 40 + ssr] = (short)hb;
      Xtl[(ddr + j) * 40 + ssr] = (short)f2b(xv[j] - b2f(hb));
    }
    __syncthreads();
    short8 afh = *(const short8*)&Wsh[(w*16 + l15)*32 + kg*8];
    short8 afl = *(const short8*)&Wsl[(w*16 + l15)*32 + kg*8];
    #pragma unroll
    for (int j = 0; j < 4; j++){
      short8 bvh = *(const short8*)&Xth[(j*16 + l15)*40 + kg*8];
      short8 bvl = *(const short8*)&Xtl[(j*16 + l15)*40 + kg*8];
      acc[j] = mfma_bf16(afh, bvh, acc[j]);
      acc[j] = mfma_bf16(afh, bvl, acc[j]);
      acc[j] = mfma_bf16(afl, bvh, acc[j]);
    }
  }
  float* Pb = P + (size_t)(b*2) * 65536;
  #pragma unroll
  for (int j = 0; j < 4; j++)
    #pragma unroll
    for (int r = 0; r < 4; r++)
      atomicAdd(&Pb[(w*16 + kg*4 + r) * 1024 + d0 + j*16 + l15], acc[j][r]);
}

DEVI void proj_bf16_body(const unsigned short* __restrict__ X0, const unsigned short* __restrict__ wxw_bf,
                         float* __restrict__ P, char* smem, int d0, int b, int s0)
{
  short* Ws = (short*)smem;             // 4096 B
  short* Xt = (short*)(smem + 4096);    // 5120 B
  const int t = threadIdx.x, w = t >> 6, lane = t & 63;
  const int l15 = lane & 15, kg = lane >> 4;
  const unsigned short* X = X0 + (size_t)b * 4096 * 1024;
  const int ssr = t >> 3, ddr = (t & 7) * 8;
  floatx4 acc[4] = {};

  for (int kk = 0; kk < 512; kk += 32){
    const int s = s0 + kk;
    short8 xv = *(const short8*)&X[(size_t)(s + ssr) * 1024 + d0 + ddr];
    __syncthreads();
    lds_dma16(&wxw_bf[(size_t)(t >> 2) * 4096 + s + (t & 3) * 8], &Ws[t*8]);
    #pragma unroll
    for (int j = 0; j < 8; j++) Xt[(ddr + j) * 40 + ssr] = xv[j];
    __syncthreads();
    short8 af = *(const short8*)&Ws[(w*16 + l15)*32 + kg*8];
    #pragma unroll
    for (int j = 0; j < 4; j++){
      short8 bv = *(const short8*)&Xt[(j*16 + l15)*40 + kg*8];
      acc[j] = mfma_bf16(af, bv, acc[j]);
    }
  }
  float* Pb = P + (size_t)(b*2 + 1) * 65536;
  #pragma unroll
  for (int j = 0; j < 4; j++)
    #pragma unroll
    for (int r = 0; r < 4; r++)
      atomicAdd(&Pb[(w*16 + kg*4 + r) * 1024 + d0 + j*16 + l15], acc[j][r]);
}

// Fused projections: z<8 -> K-proj (split, from Kx f32); z>=8 -> V-proj (bf16).
__global__ __launch_bounds__(256, 2)
void proj_fused(const float* __restrict__ Kx, const unsigned short* __restrict__ wxh,
                const unsigned short* __restrict__ wxl,
                const unsigned short* __restrict__ Vx, const unsigned short* __restrict__ wxw_bf,
                float* __restrict__ P)
{
  __shared__ __align__(16) char smem[18432];
  const int d0 = blockIdx.x * 64, b = blockIdx.y, z = blockIdx.z;
  if (z < 8) proj_split_body(Kx, wxh, wxl, P, smem, d0, b, z*512);
  else       proj_bf16_body(Vx, wxw_bf, P, smem, d0, b, (z-8)*512);
}

// ---------------------------------------------------------------------------
// Per (b,h) attention + group norm. 256 threads: wave w owns e-quarter for
// scores and g-quarter for outputs; scores round-trip through LDS.
// Masked score entries are literal ZEROS (matches reference softmax).
// ---------------------------------------------------------------------------
__global__ __launch_bounds__(256)
void attn_kernel(const float* __restrict__ P, const float* __restrict__ Qx,
                 const float* __restrict__ wxb,
                 const float* __restrict__ gnw, const float* __restrict__ gnb,
                 float* __restrict__ zs, float* __restrict__ zc)
{
  __shared__ __align__(16) float kps[64*64];   // [e][d]
  __shared__ __align__(16) float vps[64*64];   // [e][f]
  __shared__ __align__(16) float scs[64*65];   // [e][s], stride 65
  __shared__ float pm[256];
  __shared__ float ym[64];
  const int t = threadIdx.x;
  const int w = t >> 6, s = t & 63;
  const int b = blockIdx.x >> 4, h = blockIdx.x & 15;
  const float* Pk = P + (size_t)(2*b) * 65536 + h*64;
  const float* Pv = Pk + 65536;

  {
    const int e = t >> 2, c = (t & 3) * 16;
    const float wb = wxb[e];
    #pragma unroll
    for (int j = 0; j < 4; j++){
      floatx4 kv = *(const floatx4*)&Pk[(size_t)e*1024 + c + 4*j];
      floatx4 vv = *(const floatx4*)&Pv[(size_t)e*1024 + c + 4*j];
      kv.x += wb; kv.y += wb; kv.z += wb; kv.w += wb;
      vv.x += wb; vv.y += wb; vv.z += wb; vv.w += wb;
      *(floatx4*)&kps[e*64 + c + 4*j] = kv;
      *(floatx4*)&vps[e*64 + c + 4*j] = vv;
    }
  }
  __syncthreads();

  float qf[64];
  const floatx4* q4 = (const floatx4*)(Qx + (size_t)(b*64 + s)*1024 + h*64);
  #pragma unroll
  for (int i = 0; i < 16; i++){
    floatx4 qq = q4[i];
    qf[4*i] = qq.x; qf[4*i+1] = qq.y; qf[4*i+2] = qq.z; qf[4*i+3] = qq.w;
  }

  #pragma unroll
  for (int eo = 0; eo < 16; eo++){
    const int e = w*16 + eo;
    const floatx4* kp4 = (const floatx4*)&kps[e*64];
    float dot = 0.f;
    #pragma unroll
    for (int d = 0; d < 16; d++){
      floatx4 kv = kp4[d];
      dot += qf[4*d]*kv.x + qf[4*d+1]*kv.y + qf[4*d+2]*kv.z + qf[4*d+3]*kv.w;
    }
    scs[e*65 + s] = dot;
  }
  {
    float am = 0.f;
    #pragma unroll
    for (int eo = 0; eo < 16; eo++) am += vps[(w*16 + eo)*64 + s];
    pm[t] = am;
  }
  __syncthreads();

  const float lg = -3.4657359028f - 0.1848392483f * (float)h;
  const float gamma = 1.0f - __expf(lg);
  float sc[64];
  #pragma unroll
  for (int e = 0; e < 64; e++) sc[e] = scs[e*65 + s];
  float dec = 1.0f;
  #pragma unroll
  for (int e = 0; e < 64; e++){
    bool on = (e >= s);
    sc[e] = on ? sc[e]*dec : 0.0f;
    if (on) dec *= gamma;
  }
  float mx = -1e30f;
  #pragma unroll
  for (int e = 0; e < 64; e++) mx = fmaxf(mx, sc[e]);
  float Z = 0.f;
  #pragma unroll
  for (int e = 0; e < 64; e++){ sc[e] = __expf(sc[e] - mx); Z += sc[e]; }
  const float rz = 1.0f / Z;

  #pragma unroll
  for (int go = 0; go < 4; go++){
    const int g = w*4 + go;
    floatx4 y = {0.f,0.f,0.f,0.f};
    #pragma unroll
    for (int e = 0; e < 64; e++){
      floatx4 vv = *(const floatx4*)&vps[e*64 + g*4];
      y += sc[e] * vv;
    }
    y *= rz;
    float mu = (y.x + y.y + y.z + y.w) * 0.25f;
    float a0 = y.x-mu, a1 = y.y-mu, a2 = y.z-mu, a3 = y.w-mu;
    float inv = rsqrtf((a0*a0 + a1*a1 + a2*a2 + a3*a3)*0.25f + 1e-5f);
    floatx4 o;
    o.x = a0*inv*gnw[g*4+0] + gnb[g*4+0];
    o.y = a1*inv*gnw[g*4+1] + gnb[g*4+1];
    o.z = a2*inv*gnw[g*4+2] + gnb[g*4+2];
    o.w = a3*inv*gnw[g*4+3] + gnb[g*4+3];
    *(floatx4*)&zs[(size_t)(b*64 + s)*1024 + h*64 + g*4] = o;
  }

  if (w == 0)
    ym[s] = (pm[s] + pm[64+s] + pm[128+s] + pm[192+s]) * (1.0f/64.0f);
  __syncthreads();
  if (t < 16){
    float a0 = ym[t*4], a1 = ym[t*4+1], a2 = ym[t*4+2], a3 = ym[t*4+3];
    float mu = (a0+a1+a2+a3)*0.25f;
    a0 -= mu; a1 -= mu; a2 -= mu; a3 -= mu;
    float inv = rsqrtf((a0*a0+a1*a1+a2*a2+a3*a3)*0.25f + 1e-5f);
    zc[(size_t)b*1024 + h*64 + t*4+0] = a0*inv*gnw[t*4+0] + gnb[t*4+0];
    zc[(size_t)b*1024 + h*64 + t*4+1] = a1*inv*gnw[t*4+1] + gnb[t*4+1];
    zc[(size_t)b*1024 + h*64 + t*4+2] = a2*inv*gnw[t*4+2] + gnb[t*4+2];
    zc[(size_t)b*1024 + h*64 + t*4+3] = a3*inv*gnw[t*4+3] + gnb[t*4+3];
  }
}

// ---------------------------------------------------------------------------
// C(f32) = A(bf16) @ B(bf16)^T — final GEMM. BK=64, both DMA, swizzled LDS,
// XCD remap, 3 blocks/CU. 128x128 kept (m105: 128x256 regresses pure-DMA).
// ---------------------------------------------------------------------------
__global__ __launch_bounds__(256, 3)
void gemm_bt(const unsigned short* __restrict__ A, const unsigned short* __restrict__ Bw,
             float* __restrict__ C, int M, int N, int K)
{
  __shared__ __align__(16) short As[128*64];
  __shared__ __align__(16) short Bs[128*64];
  const int t    = threadIdx.x;
  const int lane = t & 63;
  const int w    = t >> 6, wm = w >> 1, wn = w & 1;
  const int l15  = lane & 15, kg = lane >> 4;
  const int sx   = (l15 & 7) * 8;
  long bmi, bni; tile_remap(bmi, bni);
  const long bm = bmi * 128, bn = bni * 128;

  const int sr = t >> 3, sc8 = (t & 7) * 8;
  const int scx = sc8 ^ ((sr & 7) * 8);
  const unsigned short *pa[4], *pb[4];
  short *la[4], *lb[4];
  #pragma unroll
  for (int u = 0; u < 4; u++){
    pa[u] = A  + (bm + sr + u*32) * (size_t)K + scx;
    pb[u] = Bw + (bn + sr + u*32) * (size_t)K + scx;
    la[u] = &As[(sr + u*32)*64 + sc8];
    lb[u] = &Bs[(sr + u*32)*64 + sc8];
  }

  floatx4 acc[4][4] = {};

  #pragma unroll
  for (int u = 0; u < 4; u++){
    lds_dma16(pa[u], la[u]);
    lds_dma16(pb[u], lb[u]);
  }

  const int NT = K >> 6;
  for (int kt = 0; kt < NT; ++kt){
    __syncthreads();
    short8 af[2][4], bv[2][4];
    #pragma unroll
    for (int ks = 0; ks < 2; ks++)
      #pragma unroll
      for (int i = 0; i < 4; i++){
        af[ks][i] = *(const short8*)&As[(wm*64 + i*16 + l15)*64 + ((ks*32 + kg*8) ^ sx)];
        bv[ks][i] = *(const short8*)&Bs[(wn*64 + i*16 + l15)*64 + ((ks*32 + kg*8) ^ sx)];
      }
    __syncthreads();
    if (kt + 1 < NT){
      const int kn = (kt + 1) << 6;
      #pragma unroll
      for (int u = 0; u < 4; u++){
        lds_dma16(pa[u] + kn, la[u]);
        lds_dma16(pb[u] + kn, lb[u]);
      }
    }
    __builtin_amdgcn_sched_barrier(0);
    #pragma unroll
    for (int ks = 0; ks < 2; ks++)
      #pragma unroll
      for (int i = 0; i < 4; i++)
        #pragma unroll
        for (int j = 0; j < 4; j++)
          acc[i][j] = mfma_bf16(af[ks][i], bv[ks][j], acc[i][j]);
  }

  #pragma unroll
  for (int i = 0; i < 4; i++){
    const long mb = bm + wm*64 + i*16 + kg*4;
    #pragma unroll
    for (int j = 0; j < 4; j++){
      const long n = bn + wn*64 + j*16 + l15;
      #pragma unroll
      for (int r = 0; r < 4; r++)
        C[(size_t)(mb + r) * N + n] = acc[i][j][r];
    }
  }
}

// ---------------------------------------------------------------------------
extern "C" void kernel_launch(void* const* d_in, const int* in_sizes, int n_in,
                              void* d_out, int out_size, void* d_ws, size_t ws_size,
                              hipStream_t stream)
{
  const float* q   = (const float*)d_in[0];
  const float* k   = (const float*)d_in[1];
  const float* v   = (const float*)d_in[2];
  const float* wq  = (const float*)d_in[3];
  const float* wk  = (const float*)d_in[4];
  const float* wv  = (const float*)d_in[5];
  const float* wo  = (const float*)d_in[6];
  const float* wg  = (const float*)d_in[7];
  const float* wxw = (const float*)d_in[8];
  const float* wxb = (const float*)d_in[9];
  const float* gnw = (const float*)d_in[10];
  const float* gnb = (const float*)d_in[11];

  // ws layout (47.2 MB). d_out (f32, 64 MB) doubles as Kx f32 scratch.
  // A0 (32 MB) triple-duty: {kh|kl half-passes} -> Vx bf16 -> Agate bf16.
  char* ws = (char*)d_ws;
  unsigned short* A0   = (unsigned short*)(ws);             // 32 MB
  unsigned short* wh   = (unsigned short*)(ws + 33554432);  // 2 MB: wk_h -> wq_h
  unsigned short* wl   = (unsigned short*)(ws + 35651584);  // 2 MB: wk_l -> wq_l
  unsigned short* wAbf = (unsigned short*)(ws + 37748736);  // 2 MB: wv -> wo
  unsigned short* wgbf = (unsigned short*)(ws + 39845888);  // 2 MB
  unsigned short* wxh  = (unsigned short*)(ws + 41943040);  // 512 KB
  unsigned short* wxl  = (unsigned short*)(ws + 42467328);  // 512 KB
  float*          P    = (float*)(ws + 42991616);           // 2 MB
  float*          zs   = (float*)(ws + 45088768);           // 1 MB
  float*          zc   = (float*)(ws + 46137344);           // 16 KB
  float*          Qx   = (float*)(ws + 46153728);           // 1 MB
  float*          Kx   = (float*)d_out;                     // 64 MB f32 scratch

  const int M = 16384, N = 1024, K = 1024;
  dim3 blk(256);

  // fused prep: weights + P-zero + k-pass0 split (was wprep + memset + cvt0)
  wprep<<<6016, blk, 0, stream>>>(wk, wh, wl, wxw, wxh, wxl, wv, wAbf, wg, wgbf,
                                  P, k, A0, A0 + 8388608);

  // K path: all-DMA 3-term GEMM (xpos fused; row offsets multiple of 4096)
  gemm_split3<<<dim3(8,64), blk, 0, stream>>>(A0, A0 + 8388608, wh, wl, Kx, 8192, N, K);
  cvt_split<<<4096, blk, 0, stream>>>(k + 8388608, A0, A0 + 8388608, 1048576);
  gemm_split3<<<dim3(8,64), blk, 0, stream>>>(A0, A0 + 8388608, wh, wl,
                                              Kx + 8388608, 8192, N, K);

  // V path: v @ wv^T -> A0 bf16 (BN=256)
  gemm_af32<0><<<dim3(4,128), blk, 0, stream>>>(v, wAbf, A0, M, N, K, nullptr, nullptr);
  // fused: wq-split (wk dead) + wo-cvt (wv dead after af32<0>)
  wprep2<<<1024, blk, 0, stream>>>(wq, wh, wl, wo, wAbf);

  // fused projections: K-proj (Kx) + V-proj (A0) -> P
  proj_fused<<<dim3(16,4,16), blk, 0, stream>>>(Kx, wxh, wxl, A0, wxh, P);

  // Q path: gather 64 rows/batch, xpos fused, attention
  gemm_split<1><<<dim3(8,2), blk, 0, stream>>>(q, wh, wl, Qx, 256, N, K);
  attn_kernel<<<64, 256, 0, stream>>>(P, Qx, wxb, gnw, gnb, zs, zc);

  // Gate path: G = silu((q @ wg^T) * z) fused in epilogue -> A0, final GEMM
  gemm_af32<1><<<dim3(4,128), blk, 0, stream>>>(q, wgbf, A0, M, N, K, zs, zc);
  gemm_bt<<<dim3(8,128), blk, 0, stream>>>(A0, wAbf, (float*)d_out, M, N, K);
}